// Round 1
// baseline (396.424 us; speedup 1.0000x reference)
//
#include <hip/hip_runtime.h>
#include <hip/hip_bf16.h>
#include <math.h>

#define T_TOK   1024
#define D_DIM   1024
#define E_NUM   8
#define F_DIM   768
#define FS_DIM  768
#define N_SLOTS 2048

// ---- workspace layout (byte offsets) ----
#define WS_SEL    0                      // int[2048]
#define WS_WTS    8192                   // float[2048]
#define WS_BUCKET 16384                  // int[8*1024]
#define WS_COUNTS 49152                  // int[8]
#define WS_OFFS   49216                  // int[9]
#define WS_HS     65536                  // float[1024*768]  (3 MB)
#define WS_HE     (65536 + 3145728)      // float[2048*768]  (6 MB)
// total ~9.3 MB

// ---------------- router: logits -> sigmoid -> top-2 -> normalized weights ----------------
__global__ __launch_bounds__(256) void router_kernel(
    const float* __restrict__ X, const float* __restrict__ Wr,
    const float* __restrict__ bias, int* __restrict__ sel, float* __restrict__ wts)
{
    int t = blockIdx.x * 4 + (threadIdx.x >> 6);
    int lane = threadIdx.x & 63;
    if (t >= T_TOK) return;
    const float* xrow = X + (size_t)t * D_DIM;
    float acc[E_NUM];
#pragma unroll
    for (int e = 0; e < E_NUM; ++e) acc[e] = 0.f;
    for (int d = lane; d < D_DIM; d += 64) {
        float xv = xrow[d];
        const float4* wr = (const float4*)(Wr + (size_t)d * E_NUM);
        float4 w0 = wr[0], w1 = wr[1];
        acc[0] += xv * w0.x; acc[1] += xv * w0.y; acc[2] += xv * w0.z; acc[3] += xv * w0.w;
        acc[4] += xv * w1.x; acc[5] += xv * w1.y; acc[6] += xv * w1.z; acc[7] += xv * w1.w;
    }
#pragma unroll
    for (int e = 0; e < E_NUM; ++e) {
#pragma unroll
        for (int off = 32; off > 0; off >>= 1)
            acc[e] += __shfl_xor(acc[e], off);
    }
    if (lane == 0) {
        float s[E_NUM], b[E_NUM];
#pragma unroll
        for (int e = 0; e < E_NUM; ++e) {
            s[e] = 1.f / (1.f + expf(-acc[e]));
            b[e] = s[e] + bias[e];
        }
        // top-2 on biased scores; ties -> lower index (strict > keeps earliest)
        int i1 = 0; float b1 = b[0];
#pragma unroll
        for (int e = 1; e < E_NUM; ++e) if (b[e] > b1) { b1 = b[e]; i1 = e; }
        int i2 = -1; float b2 = -INFINITY;
#pragma unroll
        for (int e = 0; e < E_NUM; ++e) {
            if (e == i1) continue;
            if (b[e] > b2) { b2 = b[e]; i2 = e; }
        }
        float s1 = s[i1], s2 = s[i2];
        float denom = s1 + s2 + 1e-20f;
        sel[2 * t]     = i1;
        sel[2 * t + 1] = i2;
        wts[2 * t]     = s1 / denom;   // ROUTE_SCALE = 1
        wts[2 * t + 1] = s2 / denom;
    }
}

// ---------------- dispatch: stable per-expert compaction (deterministic) ----------------
__global__ __launch_bounds__(512) void dispatch_kernel(
    const int* __restrict__ sel, int* __restrict__ bucket,
    int* __restrict__ counts, int* __restrict__ offs)
{
    int e = threadIdx.x >> 6;        // wave e handles expert e
    int lane = threadIdx.x & 63;
    int running = 0;
    for (int base = 0; base < N_SLOTS; base += 64) {
        int slot = base + lane;
        bool mine = (sel[slot] == e);
        unsigned long long mask = __ballot(mine);
        if (mine) {
            int rank = running + __popcll(mask & ((1ull << lane) - 1ull));
            bucket[e * T_TOK + rank] = slot;
        }
        running += __popcll(mask);
    }
    if (lane == 0) counts[e] = running;
    __syncthreads();
    if (threadIdx.x == 0) {
        int o = 0;
        for (int k = 0; k < E_NUM; ++k) { offs[k] = o; o += counts[k]; }
        offs[E_NUM] = o;
    }
}

// ---------------- fused SiLU-GLU GEMM: H = silu(A@Wg) * (A@Wu) ----------------
// A rows: X (plain) or gathered token rows (routed). K = 1024, N = 768.
template<bool GATHER>
__global__ __launch_bounds__(256) void glu_gemm(
    const float* __restrict__ X,
    const float* __restrict__ Wg_base, const float* __restrict__ Wu_base,
    float* __restrict__ Hout,
    const int* __restrict__ bucket, const int* __restrict__ counts,
    const int* __restrict__ offs)
{
    int e = 0, nrows = T_TOK;
    const float *Bg, *Bu;
    float* H;
    if constexpr (GATHER) {
        e = blockIdx.z;
        nrows = counts[e];
        if ((int)blockIdx.y * 64 >= nrows) return;
        Bg = Wg_base + (size_t)e * D_DIM * F_DIM;
        Bu = Wu_base + (size_t)e * D_DIM * F_DIM;
        H  = Hout + (size_t)offs[e] * F_DIM;
    } else {
        Bg = Wg_base; Bu = Wu_base; H = Hout;
    }

    __shared__ float As[16][64];
    __shared__ float Bsg[16][64];
    __shared__ float Bsu[16][64];

    const int tid  = threadIdx.x;
    const int row0 = blockIdx.y * 64;
    const int col0 = blockIdx.x * 64;

    // A staging: thread loads 4 consecutive k for one row
    const int arow = tid >> 2;
    const int acol = (tid & 3) * 4;
    int srcrow;
    {
        int p = row0 + arow;
        if constexpr (GATHER) {
            int pc = min(p, nrows - 1);
            srcrow = bucket[e * T_TOK + pc] >> 1;   // slot -> token
        } else srcrow = p;
    }
    const float* Arow = X + (size_t)srcrow * D_DIM;

    // B staging: thread loads 4 consecutive cols of one k-row
    const int brow = tid >> 4;
    const int bcol = (tid & 15) * 4;

    const int ty = tid >> 4, tx = tid & 15;
    float accg[4][4] = {{0}}, accu[4][4] = {{0}};

    for (int k0 = 0; k0 < D_DIM; k0 += 16) {
        float4 av = *(const float4*)(Arow + k0 + acol);
        As[acol + 0][arow] = av.x;
        As[acol + 1][arow] = av.y;
        As[acol + 2][arow] = av.z;
        As[acol + 3][arow] = av.w;
        const size_t boff = (size_t)(k0 + brow) * F_DIM + col0 + bcol;
        *(float4*)&Bsg[brow][bcol] = *(const float4*)(Bg + boff);
        *(float4*)&Bsu[brow][bcol] = *(const float4*)(Bu + boff);
        __syncthreads();
#pragma unroll
        for (int kk = 0; kk < 16; ++kk) {
            float4 a4 = *(const float4*)&As[kk][ty * 4];
            float4 g4 = *(const float4*)&Bsg[kk][tx * 4];
            float4 u4 = *(const float4*)&Bsu[kk][tx * 4];
            float a_[4] = {a4.x, a4.y, a4.z, a4.w};
            float g_[4] = {g4.x, g4.y, g4.z, g4.w};
            float u_[4] = {u4.x, u4.y, u4.z, u4.w};
#pragma unroll
            for (int i = 0; i < 4; ++i)
#pragma unroll
                for (int j = 0; j < 4; ++j) {
                    accg[i][j] += a_[i] * g_[j];
                    accu[i][j] += a_[i] * u_[j];
                }
        }
        __syncthreads();
    }

#pragma unroll
    for (int i = 0; i < 4; ++i) {
        int r = row0 + ty * 4 + i;
        if (GATHER && r >= nrows) continue;
        float v[4];
#pragma unroll
        for (int j = 0; j < 4; ++j) {
            float g = accg[i][j];
            float u = accu[i][j];
            v[j] = (g / (1.f + expf(-g))) * u;   // silu(g)*u
        }
        *(float4*)(H + (size_t)r * F_DIM + col0 + tx * 4) =
            make_float4(v[0], v[1], v[2], v[3]);
    }
}

// ---------------- down projection: Y = H @ Wd ----------------
// shared: plain store to out (initializes every element)
// routed: out[token] += w * Y  (atomicAdd, order-independent)
// K = 768, N = 1024 for both.
template<bool ROUTED>
__global__ __launch_bounds__(256) void down_gemm(
    const float* __restrict__ Hin, const float* __restrict__ Wd_base,
    float* __restrict__ out,
    const int* __restrict__ bucket, const int* __restrict__ counts,
    const int* __restrict__ offs, const float* __restrict__ wts)
{
    int e = 0, nrows = T_TOK;
    const float* Bm;
    const float* A;
    if constexpr (ROUTED) {
        e = blockIdx.z;
        nrows = counts[e];
        if ((int)blockIdx.y * 64 >= nrows) return;
        Bm = Wd_base + (size_t)e * F_DIM * D_DIM;
        A  = Hin + (size_t)offs[e] * F_DIM;
    } else {
        Bm = Wd_base; A = Hin;
    }

    __shared__ float As[16][64];
    __shared__ float Bs[16][64];

    const int tid  = threadIdx.x;
    const int row0 = blockIdx.y * 64;
    const int col0 = blockIdx.x * 64;

    const int arow = tid >> 2;
    const int acol = (tid & 3) * 4;
    int pc = row0 + arow;
    if (ROUTED) pc = min(pc, nrows - 1);
    const float* Arow = A + (size_t)pc * F_DIM;

    const int brow = tid >> 4;
    const int bcol = (tid & 15) * 4;

    const int ty = tid >> 4, tx = tid & 15;
    float acc[4][4] = {{0}};

    for (int k0 = 0; k0 < F_DIM; k0 += 16) {
        float4 av = *(const float4*)(Arow + k0 + acol);
        As[acol + 0][arow] = av.x;
        As[acol + 1][arow] = av.y;
        As[acol + 2][arow] = av.z;
        As[acol + 3][arow] = av.w;
        *(float4*)&Bs[brow][bcol] =
            *(const float4*)(Bm + (size_t)(k0 + brow) * D_DIM + col0 + bcol);
        __syncthreads();
#pragma unroll
        for (int kk = 0; kk < 16; ++kk) {
            float4 a4 = *(const float4*)&As[kk][ty * 4];
            float4 b4 = *(const float4*)&Bs[kk][tx * 4];
            float a_[4] = {a4.x, a4.y, a4.z, a4.w};
            float b_[4] = {b4.x, b4.y, b4.z, b4.w};
#pragma unroll
            for (int i = 0; i < 4; ++i)
#pragma unroll
                for (int j = 0; j < 4; ++j)
                    acc[i][j] += a_[i] * b_[j];
        }
        __syncthreads();
    }

#pragma unroll
    for (int i = 0; i < 4; ++i) {
        int p = row0 + ty * 4 + i;
        if constexpr (ROUTED) {
            if (p >= nrows) continue;
            int slot  = bucket[e * T_TOK + p];
            int token = slot >> 1;
            float wt  = wts[slot];
            float* orow = out + (size_t)token * D_DIM + col0 + tx * 4;
#pragma unroll
            for (int j = 0; j < 4; ++j)
                atomicAdd(orow + j, wt * acc[i][j]);
        } else {
            *(float4*)(out + (size_t)p * D_DIM + col0 + tx * 4) =
                make_float4(acc[i][0], acc[i][1], acc[i][2], acc[i][3]);
        }
    }
}

extern "C" void kernel_launch(void* const* d_in, const int* in_sizes, int n_in,
                              void* d_out, int out_size, void* d_ws, size_t ws_size,
                              hipStream_t stream) {
    const float* X    = (const float*)d_in[0];
    const float* Wr   = (const float*)d_in[1];
    const float* bias = (const float*)d_in[2];
    const float* Wg   = (const float*)d_in[3];
    const float* Wu   = (const float*)d_in[4];
    const float* Wd   = (const float*)d_in[5];
    const float* Wgs  = (const float*)d_in[6];
    const float* Wus  = (const float*)d_in[7];
    const float* Wds  = (const float*)d_in[8];
    float* out = (float*)d_out;

    char* ws = (char*)d_ws;
    int*   sel    = (int*)(ws + WS_SEL);
    float* wts    = (float*)(ws + WS_WTS);
    int*   bucket = (int*)(ws + WS_BUCKET);
    int*   counts = (int*)(ws + WS_COUNTS);
    int*   offs   = (int*)(ws + WS_OFFS);
    float* Hs     = (float*)(ws + WS_HS);
    float* He     = (float*)(ws + WS_HE);

    router_kernel<<<256, 256, 0, stream>>>(X, Wr, bias, sel, wts);
    dispatch_kernel<<<1, 512, 0, stream>>>(sel, bucket, counts, offs);

    // shared expert: Hs = silu(X@Wgs)*(X@Wus); out = Hs @ Wds (dense init of out)
    glu_gemm<false><<<dim3(FS_DIM / 64, T_TOK / 64, 1), 256, 0, stream>>>(
        X, Wgs, Wus, Hs, nullptr, nullptr, nullptr);
    down_gemm<false><<<dim3(D_DIM / 64, T_TOK / 64, 1), 256, 0, stream>>>(
        Hs, Wds, out, nullptr, nullptr, nullptr, nullptr);

    // routed experts: He = silu(Xe@Wg[e])*(Xe@Wu[e]); out[token] += w * He @ Wd[e]
    glu_gemm<true><<<dim3(F_DIM / 64, T_TOK / 64, E_NUM), 256, 0, stream>>>(
        X, Wg, Wu, He, bucket, counts, offs);
    down_gemm<true><<<dim3(D_DIM / 64, T_TOK / 64, E_NUM), 256, 0, stream>>>(
        He, Wd, out, bucket, counts, offs, wts);
}

// Round 2
// 138.444 us; speedup vs baseline: 2.8634x; 2.8634x over previous
//
#include <hip/hip_runtime.h>
#include <hip/hip_bf16.h>
#include <math.h>

#define T_TOK   1024
#define D_DIM   1024
#define E_NUM   8
#define F_DIM   768
#define N_SLOTS 2048

// ---- workspace layout (byte offsets) ----
#define WS_SEL    0                         // int[2048]
#define WS_WTS    8192                      // float[2048]
#define WS_BUCKET 16384                     // int[8*1024]
#define WS_COUNTS 49152                     // int[8]
#define WS_OFFS   49216                     // int[9]
#define WS_XP     65536                     // bf16[1024*1024]   2 MB
#define WS_HS     (WS_XP + 2097152)         // bf16[1024*768]    1.5 MB
#define WS_HE     (WS_HS + 1572864)         // bf16[2048*768]    3 MB
#define WS_WGT    (WS_HE + 3145728)         // bf16[8*768*1024]  12 MB
#define WS_WUT    (WS_WGT + 12582912)
#define WS_WDT    (WS_WUT + 12582912)       // bf16[8*1024*768]
#define WS_WGST   (WS_WDT + 12582912)       // bf16[768*1024]
#define WS_WUST   (WS_WGST + 1572864)
#define WS_WDST   (WS_WUST + 1572864)       // bf16[1024*768]
// total ~49.3 MB

typedef __attribute__((ext_vector_type(8))) short bf16x8;
typedef __attribute__((ext_vector_type(4))) float f32x4;

// bijective permutation of k within a 32-block: k=16h+4g+j -> pos=8g+4h+j.
// Applied identically to A-side (X, H) and B-side (all W^T), so MFMA's
// internal lane->k mapping cancels out (same map for A and B operands).
__device__ __forceinline__ int perm5(int k) {
    return ((k >> 2) & 3) * 8 + (k & 3) + ((k >> 4) << 2);
}

__device__ __forceinline__ unsigned short f2bf(float x) {
    unsigned int u = __float_as_uint(x);
    u += 0x7fffu + ((u >> 16) & 1u);      // RNE
    return (unsigned short)(u >> 16);
}

// ---------------- router (unchanged from round 1) ----------------
__global__ __launch_bounds__(256) void router_kernel(
    const float* __restrict__ X, const float* __restrict__ Wr,
    const float* __restrict__ bias, int* __restrict__ sel, float* __restrict__ wts)
{
    int t = blockIdx.x * 4 + (threadIdx.x >> 6);
    int lane = threadIdx.x & 63;
    if (t >= T_TOK) return;
    const float* xrow = X + (size_t)t * D_DIM;
    float acc[E_NUM];
#pragma unroll
    for (int e = 0; e < E_NUM; ++e) acc[e] = 0.f;
    for (int d = lane; d < D_DIM; d += 64) {
        float xv = xrow[d];
        const float4* wr = (const float4*)(Wr + (size_t)d * E_NUM);
        float4 w0 = wr[0], w1 = wr[1];
        acc[0] += xv * w0.x; acc[1] += xv * w0.y; acc[2] += xv * w0.z; acc[3] += xv * w0.w;
        acc[4] += xv * w1.x; acc[5] += xv * w1.y; acc[6] += xv * w1.z; acc[7] += xv * w1.w;
    }
#pragma unroll
    for (int e = 0; e < E_NUM; ++e) {
#pragma unroll
        for (int off = 32; off > 0; off >>= 1)
            acc[e] += __shfl_xor(acc[e], off);
    }
    if (lane == 0) {
        float s[E_NUM], b[E_NUM];
#pragma unroll
        for (int e = 0; e < E_NUM; ++e) {
            s[e] = 1.f / (1.f + expf(-acc[e]));
            b[e] = s[e] + bias[e];
        }
        int i1 = 0; float b1 = b[0];
#pragma unroll
        for (int e = 1; e < E_NUM; ++e) if (b[e] > b1) { b1 = b[e]; i1 = e; }
        int i2 = -1; float b2 = -INFINITY;
#pragma unroll
        for (int e = 0; e < E_NUM; ++e) {
            if (e == i1) continue;
            if (b[e] > b2) { b2 = b[e]; i2 = e; }
        }
        float s1 = s[i1], s2 = s[i2];
        float denom = s1 + s2 + 1e-20f;
        sel[2 * t]     = i1;
        sel[2 * t + 1] = i2;
        wts[2 * t]     = s1 / denom;
        wts[2 * t + 1] = s2 / denom;
    }
}

// ---------------- dispatch (unchanged) ----------------
__global__ __launch_bounds__(512) void dispatch_kernel(
    const int* __restrict__ sel, int* __restrict__ bucket,
    int* __restrict__ counts, int* __restrict__ offs)
{
    int e = threadIdx.x >> 6;
    int lane = threadIdx.x & 63;
    int running = 0;
    for (int base = 0; base < N_SLOTS; base += 64) {
        int slot = base + lane;
        bool mine = (sel[slot] == e);
        unsigned long long mask = __ballot(mine);
        if (mine) {
            int rank = running + __popcll(mask & ((1ull << lane) - 1ull));
            bucket[e * T_TOK + rank] = slot;
        }
        running += __popcll(mask);
    }
    if (lane == 0) counts[e] = running;
    __syncthreads();
    if (threadIdx.x == 0) {
        int o = 0;
        for (int k = 0; k < E_NUM; ++k) { offs[k] = o; o += counts[k]; }
        offs[E_NUM] = o;
    }
}

// ---------------- prep: transpose+cvt all weights to bf16 [N][K] (k-permuted) ----------------
__global__ __launch_bounds__(256) void transpose_cvt(
    const float* __restrict__ Wg, const float* __restrict__ Wu,
    const float* __restrict__ Wd, const float* __restrict__ Wgs,
    const float* __restrict__ Wus, const float* __restrict__ Wds,
    unsigned short* __restrict__ Wgt, unsigned short* __restrict__ Wut,
    unsigned short* __restrict__ Wdt, unsigned short* __restrict__ Wgst,
    unsigned short* __restrict__ Wust, unsigned short* __restrict__ Wdst)
{
    int z = blockIdx.z;
    const float* src; unsigned short* dst; int R, C;
    if (z < 8)       { src = Wg  + (size_t)z * D_DIM * F_DIM; dst = Wgt + (size_t)z * F_DIM * D_DIM; R = D_DIM; C = F_DIM; }
    else if (z < 16) { int e = z - 8;  src = Wu + (size_t)e * D_DIM * F_DIM; dst = Wut + (size_t)e * F_DIM * D_DIM; R = D_DIM; C = F_DIM; }
    else if (z < 24) { int e = z - 16; src = Wd + (size_t)e * F_DIM * D_DIM; dst = Wdt + (size_t)e * D_DIM * F_DIM; R = F_DIM; C = D_DIM; }
    else if (z == 24){ src = Wgs; dst = Wgst; R = D_DIM; C = F_DIM; }
    else if (z == 25){ src = Wus; dst = Wust; R = D_DIM; C = F_DIM; }
    else             { src = Wds; dst = Wdst; R = F_DIM; C = D_DIM; }
    int c0 = blockIdx.x * 64, r0 = blockIdx.y * 64;
    if (c0 >= C || r0 >= R) return;

    __shared__ unsigned short tile[64][72];   // [c][r_perm], row stride 144B (16B-mult)
    int t = threadIdx.x;
    int rr = t >> 4, cq = (t & 15) * 4;
#pragma unroll
    for (int i = 0; i < 4; ++i) {
        int rl = rr + 16 * i;                                 // local r in tile
        float4 v = *(const float4*)(src + (size_t)(r0 + rl) * C + c0 + cq);
        int rp = (rl & 32) + perm5(rl & 31);
        tile[cq + 0][rp] = f2bf(v.x);
        tile[cq + 1][rp] = f2bf(v.y);
        tile[cq + 2][rp] = f2bf(v.z);
        tile[cq + 3][rp] = f2bf(v.w);
    }
    __syncthreads();
#pragma unroll
    for (int j = 0; j < 2; ++j) {
        int idx = t + 256 * j;
        int cc = idx >> 3, q = idx & 7;
        *(uint4*)(dst + (size_t)(c0 + cc) * R + r0 + q * 8) = *(const uint4*)&tile[cc][q * 8];
    }
}

// ---------------- X -> bf16 k-permuted ----------------
__global__ __launch_bounds__(256) void xcvt_kernel(
    const float* __restrict__ X, unsigned short* __restrict__ Xp)
{
    int i4 = (blockIdx.x * 256 + threadIdx.x) * 4;
    float4 v = *(const float4*)(X + i4);
    int k = i4 & (D_DIM - 1);
    int base = (i4 & ~(D_DIM - 1)) + (k & ~31) + perm5(k & 31);
    unsigned short* p = Xp + base;
    ushort4 o; o.x = f2bf(v.x); o.y = f2bf(v.y); o.z = f2bf(v.z); o.w = f2bf(v.w);
    *(ushort4*)p = o;
}

// ---------------- fused SiLU-GLU MFMA GEMM ----------------
// block: 64 rows x 128 cols (both gate & up). z<8: routed expert z; z==8: shared.
__global__ __launch_bounds__(256) void glu_mfma(
    const unsigned short* __restrict__ Xp,
    const unsigned short* __restrict__ Wgt, const unsigned short* __restrict__ Wut,
    const unsigned short* __restrict__ Wgst, const unsigned short* __restrict__ Wust,
    unsigned short* __restrict__ He, unsigned short* __restrict__ Hs,
    const int* __restrict__ bucket, const int* __restrict__ counts,
    const int* __restrict__ offs)
{
    const int z = blockIdx.z;
    const bool gather = (z < E_NUM);
    int nrows; const unsigned short *Bg, *Bu; unsigned short* H;
    if (gather) {
        nrows = counts[z];
        if ((int)blockIdx.y * 64 >= nrows) return;
        Bg = Wgt + (size_t)z * F_DIM * D_DIM;
        Bu = Wut + (size_t)z * F_DIM * D_DIM;
        H  = He + (size_t)offs[z] * F_DIM;
    } else {
        nrows = T_TOK; Bg = Wgst; Bu = Wust; H = Hs;
    }

    __shared__ unsigned short As[64][40];
    __shared__ unsigned short Bgs[128][40];
    __shared__ unsigned short Bus[128][40];

    const int t = threadIdx.x;
    const int wv = t >> 6, l15 = t & 15, g = (t & 63) >> 4;
    const int row0 = blockIdx.y * 64;
    const int col0 = blockIdx.x * 128;

    const int arow = t >> 2, aq = t & 3;
    int srcr;
    if (gather) srcr = bucket[z * T_TOK + min(row0 + arow, nrows - 1)] >> 1;
    else        srcr = row0 + arow;
    const unsigned short* Arow = Xp + (size_t)srcr * D_DIM;

    f32x4 accg[4][2], accu[4][2];
    const f32x4 z4 = {0.f, 0.f, 0.f, 0.f};
#pragma unroll
    for (int ri = 0; ri < 4; ++ri)
#pragma unroll
        for (int ci = 0; ci < 2; ++ci) { accg[ri][ci] = z4; accu[ri][ci] = z4; }

    for (int kt = 0; kt < D_DIM; kt += 32) {
        *(uint4*)&As[arow][aq * 8] = *(const uint4*)(Arow + kt + aq * 8);
#pragma unroll
        for (int j = 0; j < 2; ++j) {
            int n = j * 64 + arow;
            size_t go = (size_t)(col0 + n) * D_DIM + kt + aq * 8;
            *(uint4*)&Bgs[n][aq * 8] = *(const uint4*)(Bg + go);
            *(uint4*)&Bus[n][aq * 8] = *(const uint4*)(Bu + go);
        }
        __syncthreads();
        bf16x8 af[4];
#pragma unroll
        for (int ri = 0; ri < 4; ++ri)
            af[ri] = *(const bf16x8*)&As[16 * ri + l15][g * 8];
#pragma unroll
        for (int ci = 0; ci < 2; ++ci) {
            int nn = 32 * wv + 16 * ci + l15;
            bf16x8 bg = *(const bf16x8*)&Bgs[nn][g * 8];
#pragma unroll
            for (int ri = 0; ri < 4; ++ri)
                accg[ri][ci] = __builtin_amdgcn_mfma_f32_16x16x32_bf16(af[ri], bg, accg[ri][ci], 0, 0, 0);
            bf16x8 bu = *(const bf16x8*)&Bus[nn][g * 8];
#pragma unroll
            for (int ri = 0; ri < 4; ++ri)
                accu[ri][ci] = __builtin_amdgcn_mfma_f32_16x16x32_bf16(af[ri], bu, accu[ri][ci], 0, 0, 0);
        }
        __syncthreads();
    }

    // epilogue: H[row][perm(f)] = bf16(silu(g)*u)
#pragma unroll
    for (int ri = 0; ri < 4; ++ri) {
#pragma unroll
        for (int ci = 0; ci < 2; ++ci) {
            int fpos = (col0 + 32 * wv) + (l15 >> 2) * 8 + (l15 & 3) + ci * 4 + ((16 * ci + l15) & 32 ? 32 : 0);
#pragma unroll
            for (int r = 0; r < 4; ++r) {
                int row = row0 + 16 * ri + 4 * g + r;
                if (gather && row >= nrows) continue;
                float gv = accg[ri][ci][r];
                float uv = accu[ri][ci][r];
                float h = gv / (1.f + __expf(-gv)) * uv;
                H[(size_t)row * F_DIM + fpos] = f2bf(h);
            }
        }
    }
}

// ---------------- down-proj MFMA GEMM, fp32 atomicAdd combine ----------------
__global__ __launch_bounds__(256) void down_mfma(
    const unsigned short* __restrict__ He, const unsigned short* __restrict__ Hs,
    const unsigned short* __restrict__ Wdt, const unsigned short* __restrict__ Wdst,
    float* __restrict__ out,
    const int* __restrict__ bucket, const int* __restrict__ counts,
    const int* __restrict__ offs, const float* __restrict__ wts)
{
    const int z = blockIdx.z;
    const bool routed = (z < E_NUM);
    int nrows; const unsigned short *A, *Bm;
    if (routed) {
        nrows = counts[z];
        if ((int)blockIdx.y * 64 >= nrows) return;
        A  = He + (size_t)offs[z] * F_DIM;
        Bm = Wdt + (size_t)z * D_DIM * F_DIM;
    } else {
        nrows = T_TOK; A = Hs; Bm = Wdst;
    }

    __shared__ unsigned short As[64][40];
    __shared__ unsigned short Bs[128][40];

    const int t = threadIdx.x;
    const int wv = t >> 6, l15 = t & 15, g = (t & 63) >> 4;
    const int row0 = blockIdx.y * 64;
    const int col0 = blockIdx.x * 128;

    const int arow = t >> 2, aq = t & 3;
    const unsigned short* Arow = A + (size_t)min(row0 + arow, nrows - 1) * F_DIM;

    f32x4 acc[4][2];
    const f32x4 z4 = {0.f, 0.f, 0.f, 0.f};
#pragma unroll
    for (int ri = 0; ri < 4; ++ri)
#pragma unroll
        for (int ci = 0; ci < 2; ++ci) acc[ri][ci] = z4;

    for (int kt = 0; kt < F_DIM; kt += 32) {
        *(uint4*)&As[arow][aq * 8] = *(const uint4*)(Arow + kt + aq * 8);
#pragma unroll
        for (int j = 0; j < 2; ++j) {
            int n = j * 64 + arow;
            *(uint4*)&Bs[n][aq * 8] = *(const uint4*)(Bm + (size_t)(col0 + n) * F_DIM + kt + aq * 8);
        }
        __syncthreads();
        bf16x8 af[4];
#pragma unroll
        for (int ri = 0; ri < 4; ++ri)
            af[ri] = *(const bf16x8*)&As[16 * ri + l15][g * 8];
#pragma unroll
        for (int ci = 0; ci < 2; ++ci) {
            bf16x8 b = *(const bf16x8*)&Bs[32 * wv + 16 * ci + l15][g * 8];
#pragma unroll
            for (int ri = 0; ri < 4; ++ri)
                acc[ri][ci] = __builtin_amdgcn_mfma_f32_16x16x32_bf16(af[ri], b, acc[ri][ci], 0, 0, 0);
        }
        __syncthreads();
    }

#pragma unroll
    for (int ri = 0; ri < 4; ++ri) {
#pragma unroll
        for (int ci = 0; ci < 2; ++ci) {
            int n = col0 + 32 * wv + 16 * ci + l15;
#pragma unroll
            for (int r = 0; r < 4; ++r) {
                int row = row0 + 16 * ri + 4 * g + r;
                if (row >= nrows) continue;
                float v = acc[ri][ci][r];
                if (routed) {
                    int slot = bucket[z * T_TOK + row];
                    atomicAdd(out + (size_t)(slot >> 1) * D_DIM + n, wts[slot] * v);
                } else {
                    atomicAdd(out + (size_t)row * D_DIM + n, v);
                }
            }
        }
    }
}

extern "C" void kernel_launch(void* const* d_in, const int* in_sizes, int n_in,
                              void* d_out, int out_size, void* d_ws, size_t ws_size,
                              hipStream_t stream) {
    const float* X    = (const float*)d_in[0];
    const float* Wr   = (const float*)d_in[1];
    const float* bias = (const float*)d_in[2];
    const float* Wg   = (const float*)d_in[3];
    const float* Wu   = (const float*)d_in[4];
    const float* Wd   = (const float*)d_in[5];
    const float* Wgs  = (const float*)d_in[6];
    const float* Wus  = (const float*)d_in[7];
    const float* Wds  = (const float*)d_in[8];
    float* out = (float*)d_out;

    char* ws = (char*)d_ws;
    int*   sel    = (int*)(ws + WS_SEL);
    float* wtsv   = (float*)(ws + WS_WTS);
    int*   bucket = (int*)(ws + WS_BUCKET);
    int*   counts = (int*)(ws + WS_COUNTS);
    int*   offs   = (int*)(ws + WS_OFFS);
    unsigned short* Xp   = (unsigned short*)(ws + WS_XP);
    unsigned short* Hs   = (unsigned short*)(ws + WS_HS);
    unsigned short* He   = (unsigned short*)(ws + WS_HE);
    unsigned short* Wgt  = (unsigned short*)(ws + WS_WGT);
    unsigned short* Wut  = (unsigned short*)(ws + WS_WUT);
    unsigned short* Wdt  = (unsigned short*)(ws + WS_WDT);
    unsigned short* Wgst = (unsigned short*)(ws + WS_WGST);
    unsigned short* Wust = (unsigned short*)(ws + WS_WUST);
    unsigned short* Wdst = (unsigned short*)(ws + WS_WDST);

    transpose_cvt<<<dim3(16, 16, 27), 256, 0, stream>>>(
        Wg, Wu, Wd, Wgs, Wus, Wds, Wgt, Wut, Wdt, Wgst, Wust, Wdst);
    xcvt_kernel<<<T_TOK * D_DIM / 4 / 256, 256, 0, stream>>>(X, Xp);
    router_kernel<<<256, 256, 0, stream>>>(X, Wr, bias, sel, wtsv);
    dispatch_kernel<<<1, 512, 0, stream>>>(sel, bucket, counts, offs);
    hipMemsetAsync(d_out, 0, (size_t)out_size * sizeof(float), stream);

    glu_mfma<<<dim3(F_DIM / 128, T_TOK / 64, E_NUM + 1), 256, 0, stream>>>(
        Xp, Wgt, Wut, Wgst, Wust, He, Hs, bucket, counts, offs);
    down_mfma<<<dim3(D_DIM / 128, T_TOK / 64, E_NUM + 1), 256, 0, stream>>>(
        He, Hs, Wdt, Wdst, out, bucket, counts, offs, wtsv);
}

// Round 3
// 121.914 us; speedup vs baseline: 3.2517x; 1.1356x over previous
//
#include <hip/hip_runtime.h>
#include <hip/hip_bf16.h>
#include <math.h>

#define T_TOK   1024
#define D_DIM   1024
#define E_NUM   8
#define F_DIM   768
#define N_SLOTS 2048

// ---- workspace layout (byte offsets) ----
#define WS_SEL    0                        // int[2048]
#define WS_WTS    8192                     // float[2048]
#define WS_BUCKET 16384                    // int[8*1024]
#define WS_COUNTS 49152                    // int[8]
#define WS_OFFS   49216                    // int[16]
#define WS_POS    49280                    // int[2048]
#define WS_XP     65536                    // bf16[1024*1024]      2 MB
#define WS_HG     (WS_XP   + 2097152)      // bf16[3072*768]       4.5 MB (routed 0..2047, shared 2048..3071)
#define WS_HU     (WS_HG   + 4718592)      // bf16[3072*768]
#define WS_Y      (WS_HU   + 4718592)      // f32 [3072*1024]      12 MB
#define WS_WGT    (WS_Y    + 12582912)     // bf16[8*768*1024]
#define WS_WUT    (WS_WGT  + 12582912)
#define WS_WDT    (WS_WUT  + 12582912)     // bf16[8*1024*768]
#define WS_WGST   (WS_WDT  + 12582912)     // bf16[768*1024]
#define WS_WUST   (WS_WGST + 1572864)
#define WS_WDST   (WS_WUST + 1572864)      // ends ~66.7 MB

typedef __attribute__((ext_vector_type(8))) short bf16x8;
typedef __attribute__((ext_vector_type(4))) float f32x4;

// bijective k-permutation within a 32-block: k=16h+4g+j -> pos=8g+4h+j.
// Applied identically to A-side (Xp, Hg/Hu) and B-side (all W^T) k-axes,
// so MFMA's internal lane->k mapping cancels out.
__device__ __forceinline__ int perm5(int k) {
    return ((k >> 2) & 3) * 8 + (k & 3) + ((k >> 4) << 2);
}

__device__ __forceinline__ unsigned short f2bf(float x) {
    unsigned int u = __float_as_uint(x);
    u += 0x7fffu + ((u >> 16) & 1u);      // RNE
    return (unsigned short)(u >> 16);
}

__device__ __forceinline__ float bf2f(unsigned short h) {
    unsigned int u = ((unsigned int)h) << 16;
    return __uint_as_float(u);
}

// ---------------- router ----------------
__global__ __launch_bounds__(256) void router_kernel(
    const float* __restrict__ X, const float* __restrict__ Wr,
    const float* __restrict__ bias, int* __restrict__ sel, float* __restrict__ wts)
{
    int t = blockIdx.x * 4 + (threadIdx.x >> 6);
    int lane = threadIdx.x & 63;
    if (t >= T_TOK) return;
    const float* xrow = X + (size_t)t * D_DIM;
    float acc[E_NUM];
#pragma unroll
    for (int e = 0; e < E_NUM; ++e) acc[e] = 0.f;
    for (int d = lane; d < D_DIM; d += 64) {
        float xv = xrow[d];
        const float4* wr = (const float4*)(Wr + (size_t)d * E_NUM);
        float4 w0 = wr[0], w1 = wr[1];
        acc[0] += xv * w0.x; acc[1] += xv * w0.y; acc[2] += xv * w0.z; acc[3] += xv * w0.w;
        acc[4] += xv * w1.x; acc[5] += xv * w1.y; acc[6] += xv * w1.z; acc[7] += xv * w1.w;
    }
#pragma unroll
    for (int e = 0; e < E_NUM; ++e) {
#pragma unroll
        for (int off = 32; off > 0; off >>= 1)
            acc[e] += __shfl_xor(acc[e], off);
    }
    if (lane == 0) {
        float s[E_NUM], b[E_NUM];
#pragma unroll
        for (int e = 0; e < E_NUM; ++e) {
            s[e] = 1.f / (1.f + expf(-acc[e]));
            b[e] = s[e] + bias[e];
        }
        int i1 = 0; float b1 = b[0];
#pragma unroll
        for (int e = 1; e < E_NUM; ++e) if (b[e] > b1) { b1 = b[e]; i1 = e; }
        int i2 = -1; float b2 = -INFINITY;
#pragma unroll
        for (int e = 0; e < E_NUM; ++e) {
            if (e == i1) continue;
            if (b[e] > b2) { b2 = b[e]; i2 = e; }
        }
        float s1 = s[i1], s2 = s[i2];
        float denom = s1 + s2 + 1e-20f;
        sel[2 * t]     = i1;
        sel[2 * t + 1] = i2;
        wts[2 * t]     = s1 / denom;
        wts[2 * t + 1] = s2 / denom;
    }
}

// ---------------- dispatch: stable per-expert compaction + inverse map ----------------
__global__ __launch_bounds__(512) void dispatch_kernel(
    const int* __restrict__ sel, int* __restrict__ bucket,
    int* __restrict__ counts, int* __restrict__ offs, int* __restrict__ pos)
{
    __shared__ int soffs[E_NUM + 1];
    int e = threadIdx.x >> 6;
    int lane = threadIdx.x & 63;
    int running = 0;
    for (int base = 0; base < N_SLOTS; base += 64) {
        int slot = base + lane;
        bool mine = (sel[slot] == e);
        unsigned long long mask = __ballot(mine);
        if (mine) {
            int rank = running + __popcll(mask & ((1ull << lane) - 1ull));
            bucket[e * T_TOK + rank] = slot;
        }
        running += __popcll(mask);
    }
    if (lane == 0) counts[e] = running;
    __syncthreads();
    if (threadIdx.x == 0) {
        int o = 0;
        for (int k = 0; k < E_NUM; ++k) { soffs[k] = o; offs[k] = o; o += counts[k]; }
        soffs[E_NUM] = o; offs[E_NUM] = o;
    }
    __syncthreads();
    int base_off = soffs[e];
    for (int r = lane; r < running; r += 64)
        pos[bucket[e * T_TOK + r]] = base_off + r;
}

// ---------------- prep: transpose+cvt all weights to bf16 [N][K] (k-permuted) ----------------
__global__ __launch_bounds__(256) void transpose_cvt(
    const float* __restrict__ Wg, const float* __restrict__ Wu,
    const float* __restrict__ Wd, const float* __restrict__ Wgs,
    const float* __restrict__ Wus, const float* __restrict__ Wds,
    unsigned short* __restrict__ Wgt, unsigned short* __restrict__ Wut,
    unsigned short* __restrict__ Wdt, unsigned short* __restrict__ Wgst,
    unsigned short* __restrict__ Wust, unsigned short* __restrict__ Wdst)
{
    int z = blockIdx.z;
    const float* src; unsigned short* dst; int R, C;
    if (z < 8)       { src = Wg  + (size_t)z * D_DIM * F_DIM; dst = Wgt + (size_t)z * F_DIM * D_DIM; R = D_DIM; C = F_DIM; }
    else if (z < 16) { int e = z - 8;  src = Wu + (size_t)e * D_DIM * F_DIM; dst = Wut + (size_t)e * F_DIM * D_DIM; R = D_DIM; C = F_DIM; }
    else if (z < 24) { int e = z - 16; src = Wd + (size_t)e * F_DIM * D_DIM; dst = Wdt + (size_t)e * D_DIM * F_DIM; R = F_DIM; C = D_DIM; }
    else if (z == 24){ src = Wgs; dst = Wgst; R = D_DIM; C = F_DIM; }
    else if (z == 25){ src = Wus; dst = Wust; R = D_DIM; C = F_DIM; }
    else             { src = Wds; dst = Wdst; R = F_DIM; C = D_DIM; }
    int c0 = blockIdx.x * 64, r0 = blockIdx.y * 64;
    if (c0 >= C || r0 >= R) return;

    __shared__ unsigned short tile[64][72];
    int t = threadIdx.x;
    int rr = t >> 4, cq = (t & 15) * 4;
#pragma unroll
    for (int i = 0; i < 4; ++i) {
        int rl = rr + 16 * i;
        float4 v = *(const float4*)(src + (size_t)(r0 + rl) * C + c0 + cq);
        int rp = (rl & 32) + perm5(rl & 31);
        tile[cq + 0][rp] = f2bf(v.x);
        tile[cq + 1][rp] = f2bf(v.y);
        tile[cq + 2][rp] = f2bf(v.z);
        tile[cq + 3][rp] = f2bf(v.w);
    }
    __syncthreads();
#pragma unroll
    for (int j = 0; j < 2; ++j) {
        int idx = t + 256 * j;
        int cc = idx >> 3, q = idx & 7;
        *(uint4*)(dst + (size_t)(c0 + cc) * R + r0 + q * 8) = *(const uint4*)&tile[cc][q * 8];
    }
}

// ---------------- X -> bf16 k-permuted ----------------
__global__ __launch_bounds__(256) void xcvt_kernel(
    const float* __restrict__ X, unsigned short* __restrict__ Xp)
{
    int i4 = (blockIdx.x * 256 + threadIdx.x) * 4;
    float4 v = *(const float4*)(X + i4);
    int k = i4 & (D_DIM - 1);
    int base = (i4 & ~(D_DIM - 1)) + (k & ~31) + perm5(k & 31);
    unsigned short* p = Xp + base;
    ushort4 o; o.x = f2bf(v.x); o.y = f2bf(v.y); o.z = f2bf(v.z); o.w = f2bf(v.w);
    *(ushort4*)p = o;
}

// ---------------- proj1: G or U = X @ W (one matrix per block), pipelined ----------------
// grid: x = F/128 = 6, y = 16, z = 18 (unit = z>>1 in [0,8]; z&1: 0=gate,1=up)
__global__ __launch_bounds__(256) void proj1(
    const unsigned short* __restrict__ Xp,
    const unsigned short* __restrict__ Wgt, const unsigned short* __restrict__ Wut,
    const unsigned short* __restrict__ Wgst, const unsigned short* __restrict__ Wust,
    unsigned short* __restrict__ Hg, unsigned short* __restrict__ Hu,
    const int* __restrict__ bucket, const int* __restrict__ counts,
    const int* __restrict__ offs)
{
    const int z = blockIdx.z;
    const int unit = z >> 1;
    const bool up = z & 1;
    int nrows; const unsigned short* B; unsigned short* H;
    if (unit < E_NUM) {
        nrows = counts[unit];
        if ((int)blockIdx.y * 64 >= nrows) return;
        B = (up ? Wut : Wgt) + (size_t)unit * F_DIM * D_DIM;
        H = (up ? Hu : Hg) + (size_t)offs[unit] * F_DIM;
    } else {
        nrows = T_TOK;
        B = up ? Wust : Wgst;
        H = (up ? Hu : Hg) + (size_t)N_SLOTS * F_DIM;
    }

    __shared__ unsigned short As[64][72];
    __shared__ unsigned short Bs[128][72];

    const int t = threadIdx.x;
    const int wv = t >> 6, l15 = t & 15, g = (t & 63) >> 4;
    const int row0 = blockIdx.y * 64;
    const int col0 = blockIdx.x * 128;

    const int arow = t >> 2, aq = t & 3;          // A: 4 thr/row, 16 k each
    int srcr;
    if (unit < E_NUM) srcr = bucket[unit * T_TOK + min(row0 + arow, nrows - 1)] >> 1;
    else              srcr = row0 + arow;
    const unsigned short* Arow = Xp + (size_t)srcr * D_DIM + aq * 16;
    const int brow = t >> 1, bq = t & 1;          // B: 2 thr/row, 32 k each
    const unsigned short* Brow = B + (size_t)(col0 + brow) * D_DIM + bq * 32;

    uint4 pa0, pa1, pb0, pb1, pb2, pb3;
#define LOADT1(kt) do { \
    pa0 = *(const uint4*)(Arow + (kt)); \
    pa1 = *(const uint4*)(Arow + (kt) + 8); \
    pb0 = *(const uint4*)(Brow + (kt)); \
    pb1 = *(const uint4*)(Brow + (kt) + 8); \
    pb2 = *(const uint4*)(Brow + (kt) + 16); \
    pb3 = *(const uint4*)(Brow + (kt) + 24); } while (0)

    LOADT1(0);

    f32x4 acc[4][2];
    const f32x4 z4 = {0.f, 0.f, 0.f, 0.f};
#pragma unroll
    for (int ri = 0; ri < 4; ++ri)
#pragma unroll
        for (int ci = 0; ci < 2; ++ci) acc[ri][ci] = z4;

    for (int it = 0; it < 16; ++it) {
        if (it) __syncthreads();
        *(uint4*)&As[arow][aq * 16]     = pa0;
        *(uint4*)&As[arow][aq * 16 + 8] = pa1;
        *(uint4*)&Bs[brow][bq * 32]      = pb0;
        *(uint4*)&Bs[brow][bq * 32 + 8]  = pb1;
        *(uint4*)&Bs[brow][bq * 32 + 16] = pb2;
        *(uint4*)&Bs[brow][bq * 32 + 24] = pb3;
        if (it < 15) LOADT1((it + 1) * 64);
        __syncthreads();
        bf16x8 af[2][4], bfr[2][2];
#pragma unroll
        for (int s = 0; s < 2; ++s) {
#pragma unroll
            for (int ri = 0; ri < 4; ++ri)
                af[s][ri] = *(const bf16x8*)&As[16 * ri + l15][s * 32 + g * 8];
#pragma unroll
            for (int ci = 0; ci < 2; ++ci)
                bfr[s][ci] = *(const bf16x8*)&Bs[32 * wv + 16 * ci + l15][s * 32 + g * 8];
        }
#pragma unroll
        for (int s = 0; s < 2; ++s)
#pragma unroll
            for (int ci = 0; ci < 2; ++ci)
#pragma unroll
                for (int ri = 0; ri < 4; ++ri)
                    acc[ri][ci] = __builtin_amdgcn_mfma_f32_16x16x32_bf16(
                        af[s][ri], bfr[s][ci], acc[ri][ci], 0, 0, 0);
    }
#undef LOADT1

    // store bf16 partial (gate or up) at k-permuted f positions
#pragma unroll
    for (int ri = 0; ri < 4; ++ri)
#pragma unroll
        for (int ci = 0; ci < 2; ++ci) {
            int fpos = col0 + 32 * wv + 8 * (l15 >> 2) + (l15 & 3) + 4 * ci;
#pragma unroll
            for (int r = 0; r < 4; ++r) {
                int row = row0 + 16 * ri + 4 * g + r;
                if (unit < E_NUM && row >= nrows) continue;
                H[(size_t)row * F_DIM + fpos] = f2bf(acc[ri][ci][r]);
            }
        }
}

// ---------------- proj2: Y = (silu(G)*U) @ Wd, dense fp32 writes ----------------
// grid: x = D/128 = 8, y = 16, z = 9 units
__global__ __launch_bounds__(256) void proj2(
    const unsigned short* __restrict__ Hg, const unsigned short* __restrict__ Hu,
    const unsigned short* __restrict__ Wdt, const unsigned short* __restrict__ Wdst,
    float* __restrict__ Y,
    const int* __restrict__ counts, const int* __restrict__ offs)
{
    const int unit = blockIdx.z;
    int nrows, rbase; const unsigned short* B;
    if (unit < E_NUM) {
        nrows = counts[unit];
        if ((int)blockIdx.y * 64 >= nrows) return;
        rbase = offs[unit];
        B = Wdt + (size_t)unit * D_DIM * F_DIM;
    } else {
        nrows = T_TOK; rbase = N_SLOTS; B = Wdst;
    }

    __shared__ unsigned short As[64][72];
    __shared__ unsigned short Bs[128][72];

    const int t = threadIdx.x;
    const int wv = t >> 6, l15 = t & 15, g = (t & 63) >> 4;
    const int row0 = blockIdx.y * 64;
    const int col0 = blockIdx.x * 128;

    const int arow = t >> 2, aq = t & 3;
    const size_t hoff = (size_t)(rbase + min(row0 + arow, nrows - 1)) * F_DIM + aq * 16;
    const unsigned short* Ag = Hg + hoff;
    const unsigned short* Au = Hu + hoff;
    const int brow = t >> 1, bq = t & 1;
    const unsigned short* Brow = B + (size_t)(col0 + brow) * F_DIM + bq * 32;

    uint4 pg0, pg1, pu0, pu1, pb0, pb1, pb2, pb3;
#define LOADT2(kt) do { \
    pg0 = *(const uint4*)(Ag + (kt)); \
    pg1 = *(const uint4*)(Ag + (kt) + 8); \
    pu0 = *(const uint4*)(Au + (kt)); \
    pu1 = *(const uint4*)(Au + (kt) + 8); \
    pb0 = *(const uint4*)(Brow + (kt)); \
    pb1 = *(const uint4*)(Brow + (kt) + 8); \
    pb2 = *(const uint4*)(Brow + (kt) + 16); \
    pb3 = *(const uint4*)(Brow + (kt) + 24); } while (0)

    LOADT2(0);

    f32x4 acc[4][2];
    const f32x4 z4 = {0.f, 0.f, 0.f, 0.f};
#pragma unroll
    for (int ri = 0; ri < 4; ++ri)
#pragma unroll
        for (int ci = 0; ci < 2; ++ci) acc[ri][ci] = z4;

    for (int it = 0; it < 12; ++it) {
        if (it) __syncthreads();
        // fused SiLU-GLU on the A tile during staging
        {
            const unsigned short* gs = (const unsigned short*)&pg0;
            const unsigned short* us = (const unsigned short*)&pu0;
            ushort4 o0[2], o1[2];
#pragma unroll
            for (int half = 0; half < 2; ++half) {
                const unsigned short* gp = half ? (const unsigned short*)&pg1 : gs;
                const unsigned short* upp = half ? (const unsigned short*)&pu1 : us;
#pragma unroll
                for (int j = 0; j < 8; ++j) {
                    float gv = bf2f(gp[j]);
                    float uv = bf2f(upp[j]);
                    float h = gv / (1.f + __expf(-gv)) * uv;
                    ((unsigned short*)&o0[half >> 1])[(half & 1) * 8 + j] = 0; // placeholder avoid
                }
            }
            // (rewritten cleanly below)
        }
        // --- clean fused staging ---
        {
            unsigned short hv[16];
            const unsigned short* gp0 = (const unsigned short*)&pg0;
            const unsigned short* gp1 = (const unsigned short*)&pg1;
            const unsigned short* up0 = (const unsigned short*)&pu0;
            const unsigned short* up1 = (const unsigned short*)&pu1;
#pragma unroll
            for (int j = 0; j < 8; ++j) {
                float gv = bf2f(gp0[j]);
                float uv = bf2f(up0[j]);
                hv[j] = f2bf(gv / (1.f + __expf(-gv)) * uv);
            }
#pragma unroll
            for (int j = 0; j < 8; ++j) {
                float gv = bf2f(gp1[j]);
                float uv = bf2f(up1[j]);
                hv[8 + j] = f2bf(gv / (1.f + __expf(-gv)) * uv);
            }
            *(uint4*)&As[arow][aq * 16]     = *(const uint4*)&hv[0];
            *(uint4*)&As[arow][aq * 16 + 8] = *(const uint4*)&hv[8];
        }
        *(uint4*)&Bs[brow][bq * 32]      = pb0;
        *(uint4*)&Bs[brow][bq * 32 + 8]  = pb1;
        *(uint4*)&Bs[brow][bq * 32 + 16] = pb2;
        *(uint4*)&Bs[brow][bq * 32 + 24] = pb3;
        if (it < 11) LOADT2((it + 1) * 64);
        __syncthreads();
        bf16x8 af[2][4], bfr[2][2];
#pragma unroll
        for (int s = 0; s < 2; ++s) {
#pragma unroll
            for (int ri = 0; ri < 4; ++ri)
                af[s][ri] = *(const bf16x8*)&As[16 * ri + l15][s * 32 + g * 8];
#pragma unroll
            for (int ci = 0; ci < 2; ++ci)
                bfr[s][ci] = *(const bf16x8*)&Bs[32 * wv + 16 * ci + l15][s * 32 + g * 8];
        }
#pragma unroll
        for (int s = 0; s < 2; ++s)
#pragma unroll
            for (int ci = 0; ci < 2; ++ci)
#pragma unroll
                for (int ri = 0; ri < 4; ++ri)
                    acc[ri][ci] = __builtin_amdgcn_mfma_f32_16x16x32_bf16(
                        af[s][ri], bfr[s][ci], acc[ri][ci], 0, 0, 0);
    }
#undef LOADT2

#pragma unroll
    for (int ri = 0; ri < 4; ++ri)
#pragma unroll
        for (int ci = 0; ci < 2; ++ci) {
            int n = col0 + 32 * wv + 16 * ci + l15;
#pragma unroll
            for (int r = 0; r < 4; ++r) {
                int row = row0 + 16 * ri + 4 * g + r;
                if (row >= nrows) continue;
                Y[(size_t)(rbase + row) * D_DIM + n] = acc[ri][ci][r];
            }
        }
}

// ---------------- combine: out[t] = Yshared[t] + w0*Y[p0] + w1*Y[p1] ----------------
__global__ __launch_bounds__(256) void combine_kernel(
    const float* __restrict__ Y, const int* __restrict__ pos,
    const float* __restrict__ wts, float* __restrict__ out)
{
    int t = blockIdx.x;
    int d = threadIdx.x * 4;
    int p0 = pos[2 * t], p1 = pos[2 * t + 1];
    float w0 = wts[2 * t], w1 = wts[2 * t + 1];
    float4 a = *(const float4*)(Y + (size_t)(N_SLOTS + t) * D_DIM + d);
    float4 b = *(const float4*)(Y + (size_t)p0 * D_DIM + d);
    float4 c = *(const float4*)(Y + (size_t)p1 * D_DIM + d);
    float4 o;
    o.x = a.x + w0 * b.x + w1 * c.x;
    o.y = a.y + w0 * b.y + w1 * c.y;
    o.z = a.z + w0 * b.z + w1 * c.z;
    o.w = a.w + w0 * b.w + w1 * c.w;
    *(float4*)(out + (size_t)t * D_DIM + d) = o;
}

extern "C" void kernel_launch(void* const* d_in, const int* in_sizes, int n_in,
                              void* d_out, int out_size, void* d_ws, size_t ws_size,
                              hipStream_t stream) {
    const float* X    = (const float*)d_in[0];
    const float* Wr   = (const float*)d_in[1];
    const float* bias = (const float*)d_in[2];
    const float* Wg   = (const float*)d_in[3];
    const float* Wu   = (const float*)d_in[4];
    const float* Wd   = (const float*)d_in[5];
    const float* Wgs  = (const float*)d_in[6];
    const float* Wus  = (const float*)d_in[7];
    const float* Wds  = (const float*)d_in[8];
    float* out = (float*)d_out;

    char* ws = (char*)d_ws;
    int*   sel    = (int*)(ws + WS_SEL);
    float* wtsv   = (float*)(ws + WS_WTS);
    int*   bucket = (int*)(ws + WS_BUCKET);
    int*   counts = (int*)(ws + WS_COUNTS);
    int*   offs   = (int*)(ws + WS_OFFS);
    int*   pos    = (int*)(ws + WS_POS);
    unsigned short* Xp   = (unsigned short*)(ws + WS_XP);
    unsigned short* Hg   = (unsigned short*)(ws + WS_HG);
    unsigned short* Hu   = (unsigned short*)(ws + WS_HU);
    float*          Y    = (float*)(ws + WS_Y);
    unsigned short* Wgt  = (unsigned short*)(ws + WS_WGT);
    unsigned short* Wut  = (unsigned short*)(ws + WS_WUT);
    unsigned short* Wdt  = (unsigned short*)(ws + WS_WDT);
    unsigned short* Wgst = (unsigned short*)(ws + WS_WGST);
    unsigned short* Wust = (unsigned short*)(ws + WS_WUST);
    unsigned short* Wdst = (unsigned short*)(ws + WS_WDST);

    transpose_cvt<<<dim3(16, 16, 27), 256, 0, stream>>>(
        Wg, Wu, Wd, Wgs, Wus, Wds, Wgt, Wut, Wdt, Wgst, Wust, Wdst);
    xcvt_kernel<<<T_TOK * D_DIM / 4 / 256, 256, 0, stream>>>(X, Xp);
    router_kernel<<<256, 256, 0, stream>>>(X, Wr, bias, sel, wtsv);
    dispatch_kernel<<<1, 512, 0, stream>>>(sel, bucket, counts, offs, pos);

    proj1<<<dim3(F_DIM / 128, 16, 2 * (E_NUM + 1)), 256, 0, stream>>>(
        Xp, Wgt, Wut, Wgst, Wust, Hg, Hu, bucket, counts, offs);
    proj2<<<dim3(D_DIM / 128, 16, E_NUM + 1), 256, 0, stream>>>(
        Hg, Hu, Wdt, Wdst, Y, counts, offs);
    combine_kernel<<<T_TOK, 256, 0, stream>>>(Y, pos, wtsv, out);
}

// Round 4
// 121.203 us; speedup vs baseline: 3.2707x; 1.0059x over previous
//
#include <hip/hip_runtime.h>
#include <hip/hip_bf16.h>
#include <math.h>

#define T_TOK   1024
#define D_DIM   1024
#define E_NUM   8
#define F_DIM   768
#define N_SLOTS 2048

// ---- workspace layout (byte offsets) ----
#define WS_SEL    0                        // int[2048]
#define WS_WTS    8192                     // float[2048]
#define WS_BUCKET 16384                    // int[8*1024]
#define WS_COUNTS 49152                    // int[8]
#define WS_OFFS   49216                    // int[16]
#define WS_POS    49280                    // int[2048]
#define WS_HG     65536                    // bf16[3072*768]  (routed 0..2047, shared 2048..3071)
#define WS_HU     (WS_HG + 4718592)        // bf16[3072*768]
#define WS_Y      (WS_HU + 4718592)        // f32 [3072*1024]
// total ~22 MB

typedef __attribute__((ext_vector_type(8))) short bf16x8;
typedef __attribute__((ext_vector_type(4))) float f32x4;

__device__ __forceinline__ unsigned short f2bf(float x) {
    unsigned int u = __float_as_uint(x);
    u += 0x7fffu + ((u >> 16) & 1u);      // RNE
    return (unsigned short)(u >> 16);
}
__device__ __forceinline__ float bf2f(unsigned short h) {
    return __uint_as_float(((unsigned int)h) << 16);
}

// ---------------- router ----------------
__global__ __launch_bounds__(256) void router_kernel(
    const float* __restrict__ X, const float* __restrict__ Wr,
    const float* __restrict__ bias, int* __restrict__ sel, float* __restrict__ wts)
{
    int t = blockIdx.x * 4 + (threadIdx.x >> 6);
    int lane = threadIdx.x & 63;
    if (t >= T_TOK) return;
    const float* xrow = X + (size_t)t * D_DIM;
    float acc[E_NUM];
#pragma unroll
    for (int e = 0; e < E_NUM; ++e) acc[e] = 0.f;
    for (int d = lane; d < D_DIM; d += 64) {
        float xv = xrow[d];
        const float4* wr = (const float4*)(Wr + (size_t)d * E_NUM);
        float4 w0 = wr[0], w1 = wr[1];
        acc[0] += xv * w0.x; acc[1] += xv * w0.y; acc[2] += xv * w0.z; acc[3] += xv * w0.w;
        acc[4] += xv * w1.x; acc[5] += xv * w1.y; acc[6] += xv * w1.z; acc[7] += xv * w1.w;
    }
#pragma unroll
    for (int e = 0; e < E_NUM; ++e) {
#pragma unroll
        for (int off = 32; off > 0; off >>= 1)
            acc[e] += __shfl_xor(acc[e], off);
    }
    if (lane == 0) {
        float s[E_NUM], b[E_NUM];
#pragma unroll
        for (int e = 0; e < E_NUM; ++e) {
            s[e] = 1.f / (1.f + expf(-acc[e]));
            b[e] = s[e] + bias[e];
        }
        int i1 = 0; float b1 = b[0];
#pragma unroll
        for (int e = 1; e < E_NUM; ++e) if (b[e] > b1) { b1 = b[e]; i1 = e; }
        int i2 = -1; float b2 = -INFINITY;
#pragma unroll
        for (int e = 0; e < E_NUM; ++e) {
            if (e == i1) continue;
            if (b[e] > b2) { b2 = b[e]; i2 = e; }
        }
        float s1 = s[i1], s2 = s[i2];
        float denom = s1 + s2 + 1e-20f;
        sel[2 * t]     = i1;
        sel[2 * t + 1] = i2;
        wts[2 * t]     = s1 / denom;
        wts[2 * t + 1] = s2 / denom;
    }
}

// ---------------- dispatch: stable per-expert compaction + inverse map ----------------
__global__ __launch_bounds__(512) void dispatch_kernel(
    const int* __restrict__ sel, int* __restrict__ bucket,
    int* __restrict__ counts, int* __restrict__ offs, int* __restrict__ pos)
{
    __shared__ int soffs[E_NUM + 1];
    int e = threadIdx.x >> 6;
    int lane = threadIdx.x & 63;
    int running = 0;
    for (int base = 0; base < N_SLOTS; base += 64) {
        int slot = base + lane;
        bool mine = (sel[slot] == e);
        unsigned long long mask = __ballot(mine);
        if (mine) {
            int rank = running + __popcll(mask & ((1ull << lane) - 1ull));
            bucket[e * T_TOK + rank] = slot;
        }
        running += __popcll(mask);
    }
    if (lane == 0) counts[e] = running;
    __syncthreads();
    if (threadIdx.x == 0) {
        int o = 0;
        for (int k = 0; k < E_NUM; ++k) { soffs[k] = o; offs[k] = o; o += counts[k]; }
        soffs[E_NUM] = o; offs[E_NUM] = o;
    }
    __syncthreads();
    int base_off = soffs[e];
    for (int r = lane; r < running; r += 64)
        pos[bucket[e * T_TOK + r]] = base_off + r;
}

// ================= proj1: G or U = X @ W, fp32 weights read directly =================
// 64x64 tile, BK=64, 2-deep reg prefetch, double-buffered LDS, XCD panel swizzle.
// work decode: p = panel id (z*12+x), z in [0,18): unit=z>>1, up=z&1; y = row tile.
struct P1Stage { float4 a[4]; float b[16]; };

__global__ __launch_bounds__(256) void proj1(
    const float* __restrict__ X,
    const float* __restrict__ Wg, const float* __restrict__ Wu,
    const float* __restrict__ Wgs, const float* __restrict__ Wus,
    unsigned short* __restrict__ Hg, unsigned short* __restrict__ Hu,
    const int* __restrict__ bucket, const int* __restrict__ counts,
    const int* __restrict__ offs)
{
    const int i = blockIdx.x;
    const int c = i & 7, m = i >> 3;
    const int y = m & 15, phi = m >> 4;
    const int p = phi * 8 + c;            // 0..215
    const int z = p / 12, x = p - z * 12; // z 0..17, x 0..11
    const int unit = z >> 1, up = z & 1;

    int nrows; const float* B; unsigned short* H;
    if (unit < E_NUM) {
        nrows = counts[unit];
        B = (up ? Wu : Wg) + (size_t)unit * D_DIM * F_DIM;
        H = (up ? Hu : Hg) + (size_t)offs[unit] * F_DIM;
    } else {
        nrows = T_TOK;
        B = up ? Wus : Wgs;
        H = (up ? Hu : Hg) + (size_t)N_SLOTS * F_DIM;
    }
    const int row0 = y * 64, col0 = x * 64;
    if (row0 >= nrows) return;

    __shared__ unsigned short As[2][64][72];
    __shared__ unsigned short Bs[2][64][72];

    const int t = threadIdx.x;
    const int wv = t >> 6, l15 = t & 15, g = (t & 63) >> 4;

    const int arow = t >> 2, aq = t & 3;
    int srcr;
    if (unit < E_NUM) srcr = bucket[unit * T_TOK + min(row0 + arow, nrows - 1)] >> 1;
    else              srcr = row0 + arow;
    const float* Ap = X + (size_t)srcr * D_DIM + aq * 16;

    const int bn = t & 63, bk = (t >> 6) * 16;
    const float* Bp = B + (size_t)bk * F_DIM + col0 + bn;

    f32x4 acc[2][2];
    const f32x4 z4 = {0.f, 0.f, 0.f, 0.f};
#pragma unroll
    for (int ri = 0; ri < 2; ++ri)
#pragma unroll
        for (int ci = 0; ci < 2; ++ci) acc[ri][ci] = z4;

    auto loadStage = [&](P1Stage& S, int k0) {
        const float* ap = Ap + k0;
        S.a[0] = *(const float4*)(ap);
        S.a[1] = *(const float4*)(ap + 4);
        S.a[2] = *(const float4*)(ap + 8);
        S.a[3] = *(const float4*)(ap + 12);
        const float* bp = Bp + (size_t)k0 * F_DIM;
#pragma unroll
        for (int ii = 0; ii < 16; ++ii) S.b[ii] = bp[(size_t)ii * F_DIM];
    };
    auto writeStage = [&](const P1Stage& S, int buf) {
        unsigned short ha[16];
#pragma unroll
        for (int q = 0; q < 4; ++q) {
            ha[4*q+0] = f2bf(S.a[q].x); ha[4*q+1] = f2bf(S.a[q].y);
            ha[4*q+2] = f2bf(S.a[q].z); ha[4*q+3] = f2bf(S.a[q].w);
        }
        *(uint4*)&As[buf][arow][aq * 16]     = *(const uint4*)&ha[0];
        *(uint4*)&As[buf][arow][aq * 16 + 8] = *(const uint4*)&ha[8];
        unsigned short hb[16];
#pragma unroll
        for (int ii = 0; ii < 16; ++ii) hb[ii] = f2bf(S.b[ii]);
        *(uint4*)&Bs[buf][bn][bk]     = *(const uint4*)&hb[0];
        *(uint4*)&Bs[buf][bn][bk + 8] = *(const uint4*)&hb[8];
    };
    auto compute = [&](int buf) {
#pragma unroll
        for (int s = 0; s < 2; ++s) {
            bf16x8 af[2], bb[2];
#pragma unroll
            for (int ri = 0; ri < 2; ++ri)
                af[ri] = *(const bf16x8*)&As[buf][32 * (wv >> 1) + 16 * ri + l15][s * 32 + g * 8];
#pragma unroll
            for (int ci = 0; ci < 2; ++ci)
                bb[ci] = *(const bf16x8*)&Bs[buf][32 * (wv & 1) + 16 * ci + l15][s * 32 + g * 8];
#pragma unroll
            for (int ri = 0; ri < 2; ++ri)
#pragma unroll
                for (int ci = 0; ci < 2; ++ci)
                    acc[ri][ci] = __builtin_amdgcn_mfma_f32_16x16x32_bf16(
                        af[ri], bb[ci], acc[ri][ci], 0, 0, 0);
        }
    };

    P1Stage S0, S1;
    loadStage(S0, 0);
    loadStage(S1, 64);
    for (int it = 0; it < 16; it += 2) {
        writeStage(S0, 0);
        if (it + 2 < 16) loadStage(S0, (it + 2) * 64);
        __syncthreads();
        compute(0);
        writeStage(S1, 1);
        if (it + 3 < 16) loadStage(S1, (it + 3) * 64);
        __syncthreads();
        compute(1);
    }

#pragma unroll
    for (int ri = 0; ri < 2; ++ri)
#pragma unroll
        for (int ci = 0; ci < 2; ++ci) {
            int f = col0 + 32 * (wv & 1) + 16 * ci + l15;
#pragma unroll
            for (int r = 0; r < 4; ++r) {
                int row = row0 + 32 * (wv >> 1) + 16 * ri + 4 * g + r;
                if (unit < E_NUM && row >= nrows) continue;
                H[(size_t)row * F_DIM + f] = f2bf(acc[ri][ci][r]);
            }
        }
}

// ================= proj2: Y = (silu(G)*U) @ Wd, fp32 weights read directly =================
struct P2Stage { uint4 gg[2]; uint4 uu[2]; float b[16]; };

__global__ __launch_bounds__(256) void proj2(
    const unsigned short* __restrict__ Hg, const unsigned short* __restrict__ Hu,
    const float* __restrict__ Wd, const float* __restrict__ Wds,
    float* __restrict__ Y,
    const int* __restrict__ counts, const int* __restrict__ offs)
{
    const int i = blockIdx.x;
    const int c = i & 7, m = i >> 3;
    const int y = m & 15, phi = m >> 4;
    const int p = phi * 8 + c;            // 0..143
    const int z = p >> 4, x = p & 15;     // z 0..8, x 0..15

    int nrows, rbase; const float* B;
    if (z < E_NUM) {
        nrows = counts[z];
        rbase = offs[z];
        B = Wd + (size_t)z * F_DIM * D_DIM;
    } else {
        nrows = T_TOK; rbase = N_SLOTS; B = Wds;
    }
    const int row0 = y * 64, col0 = x * 64;
    if (row0 >= nrows) return;

    __shared__ unsigned short As[2][64][72];
    __shared__ unsigned short Bs[2][64][72];

    const int t = threadIdx.x;
    const int wv = t >> 6, l15 = t & 15, g = (t & 63) >> 4;

    const int arow = t >> 2, aq = t & 3;
    const size_t hbase = (size_t)(rbase + min(row0 + arow, nrows - 1)) * F_DIM + aq * 16;
    const unsigned short* Gp = Hg + hbase;
    const unsigned short* Up = Hu + hbase;

    const int bn = t & 63, bk = (t >> 6) * 16;
    const float* Bp = B + (size_t)bk * D_DIM + col0 + bn;

    f32x4 acc[2][2];
    const f32x4 z4 = {0.f, 0.f, 0.f, 0.f};
#pragma unroll
    for (int ri = 0; ri < 2; ++ri)
#pragma unroll
        for (int ci = 0; ci < 2; ++ci) acc[ri][ci] = z4;

    auto loadStage = [&](P2Stage& S, int k0) {
        S.gg[0] = *(const uint4*)(Gp + k0);
        S.gg[1] = *(const uint4*)(Gp + k0 + 8);
        S.uu[0] = *(const uint4*)(Up + k0);
        S.uu[1] = *(const uint4*)(Up + k0 + 8);
        const float* bp = Bp + (size_t)k0 * D_DIM;
#pragma unroll
        for (int ii = 0; ii < 16; ++ii) S.b[ii] = bp[(size_t)ii * D_DIM];
    };
    auto writeStage = [&](const P2Stage& S, int buf) {
        const unsigned short* gp = (const unsigned short*)&S.gg[0];
        const unsigned short* upp = (const unsigned short*)&S.uu[0];
        unsigned short hv[16];
#pragma unroll
        for (int j = 0; j < 16; ++j) {
            float gv = bf2f(gp[j]);
            float uv = bf2f(upp[j]);
            hv[j] = f2bf(gv / (1.f + __expf(-gv)) * uv);
        }
        *(uint4*)&As[buf][arow][aq * 16]     = *(const uint4*)&hv[0];
        *(uint4*)&As[buf][arow][aq * 16 + 8] = *(const uint4*)&hv[8];
        unsigned short hb[16];
#pragma unroll
        for (int ii = 0; ii < 16; ++ii) hb[ii] = f2bf(S.b[ii]);
        *(uint4*)&Bs[buf][bn][bk]     = *(const uint4*)&hb[0];
        *(uint4*)&Bs[buf][bn][bk + 8] = *(const uint4*)&hb[8];
    };
    auto compute = [&](int buf) {
#pragma unroll
        for (int s = 0; s < 2; ++s) {
            bf16x8 af[2], bb[2];
#pragma unroll
            for (int ri = 0; ri < 2; ++ri)
                af[ri] = *(const bf16x8*)&As[buf][32 * (wv >> 1) + 16 * ri + l15][s * 32 + g * 8];
#pragma unroll
            for (int ci = 0; ci < 2; ++ci)
                bb[ci] = *(const bf16x8*)&Bs[buf][32 * (wv & 1) + 16 * ci + l15][s * 32 + g * 8];
#pragma unroll
            for (int ri = 0; ri < 2; ++ri)
#pragma unroll
                for (int ci = 0; ci < 2; ++ci)
                    acc[ri][ci] = __builtin_amdgcn_mfma_f32_16x16x32_bf16(
                        af[ri], bb[ci], acc[ri][ci], 0, 0, 0);
        }
    };

    P2Stage S0, S1;
    loadStage(S0, 0);
    loadStage(S1, 64);
    for (int it = 0; it < 12; it += 2) {
        writeStage(S0, 0);
        if (it + 2 < 12) loadStage(S0, (it + 2) * 64);
        __syncthreads();
        compute(0);
        writeStage(S1, 1);
        if (it + 3 < 12) loadStage(S1, (it + 3) * 64);
        __syncthreads();
        compute(1);
    }

#pragma unroll
    for (int ri = 0; ri < 2; ++ri)
#pragma unroll
        for (int ci = 0; ci < 2; ++ci) {
            int n = col0 + 32 * (wv & 1) + 16 * ci + l15;
#pragma unroll
            for (int r = 0; r < 4; ++r) {
                int row = row0 + 32 * (wv >> 1) + 16 * ri + 4 * g + r;
                if (row >= nrows) continue;
                Y[(size_t)(rbase + row) * D_DIM + n] = acc[ri][ci][r];
            }
        }
}

// ---------------- combine: out[t] = Yshared[t] + w0*Y[p0] + w1*Y[p1] ----------------
__global__ __launch_bounds__(256) void combine_kernel(
    const float* __restrict__ Y, const int* __restrict__ pos,
    const float* __restrict__ wts, float* __restrict__ out)
{
    int t = blockIdx.x;
    int d = threadIdx.x * 4;
    int p0 = pos[2 * t], p1 = pos[2 * t + 1];
    float w0 = wts[2 * t], w1 = wts[2 * t + 1];
    float4 a = *(const float4*)(Y + (size_t)(N_SLOTS + t) * D_DIM + d);
    float4 b = *(const float4*)(Y + (size_t)p0 * D_DIM + d);
    float4 cc = *(const float4*)(Y + (size_t)p1 * D_DIM + d);
    float4 o;
    o.x = a.x + w0 * b.x + w1 * cc.x;
    o.y = a.y + w0 * b.y + w1 * cc.y;
    o.z = a.z + w0 * b.z + w1 * cc.z;
    o.w = a.w + w0 * b.w + w1 * cc.w;
    *(float4*)(out + (size_t)t * D_DIM + d) = o;
}

extern "C" void kernel_launch(void* const* d_in, const int* in_sizes, int n_in,
                              void* d_out, int out_size, void* d_ws, size_t ws_size,
                              hipStream_t stream) {
    const float* X    = (const float*)d_in[0];
    const float* Wr   = (const float*)d_in[1];
    const float* bias = (const float*)d_in[2];
    const float* Wg   = (const float*)d_in[3];
    const float* Wu   = (const float*)d_in[4];
    const float* Wd   = (const float*)d_in[5];
    const float* Wgs  = (const float*)d_in[6];
    const float* Wus  = (const float*)d_in[7];
    const float* Wds  = (const float*)d_in[8];
    float* out = (float*)d_out;

    char* ws = (char*)d_ws;
    int*   sel    = (int*)(ws + WS_SEL);
    float* wtsv   = (float*)(ws + WS_WTS);
    int*   bucket = (int*)(ws + WS_BUCKET);
    int*   counts = (int*)(ws + WS_COUNTS);
    int*   offs   = (int*)(ws + WS_OFFS);
    int*   pos    = (int*)(ws + WS_POS);
    unsigned short* Hg = (unsigned short*)(ws + WS_HG);
    unsigned short* Hu = (unsigned short*)(ws + WS_HU);
    float*          Y  = (float*)(ws + WS_Y);

    router_kernel<<<256, 256, 0, stream>>>(X, Wr, bias, sel, wtsv);
    dispatch_kernel<<<1, 512, 0, stream>>>(sel, bucket, counts, offs, pos);

    proj1<<<216 * 16, 256, 0, stream>>>(
        X, Wg, Wu, Wgs, Wus, Hg, Hu, bucket, counts, offs);
    proj2<<<144 * 16, 256, 0, stream>>>(
        Hg, Hu, Wd, Wds, Y, counts, offs);
    combine_kernel<<<T_TOK, 256, 0, stream>>>(Y, pos, wtsv, out);
}

// Round 5
// 99.740 us; speedup vs baseline: 3.9746x; 1.2152x over previous
//
#include <hip/hip_runtime.h>
#include <hip/hip_bf16.h>
#include <math.h>

#define T_TOK   1024
#define D_DIM   1024
#define E_NUM   8
#define F_DIM   768
#define N_SLOTS 2048

typedef unsigned short u16;
typedef __attribute__((ext_vector_type(8))) short bf16x8;
typedef __attribute__((ext_vector_type(4))) float f32x4;

// ---- workspace layout (byte offsets) ----
#define WS_SEL    0
#define WS_WTS    8192
#define WS_BUCKET 16384
#define WS_COUNTS 49152
#define WS_OFFS   49216
#define WS_POS    49280
#define WS_XB     65536                      // bf16[1024][1024]      2 MB
#define WS_P1     (WS_XB + 2097152)          // bf16[3072][1536]      9.4 MB
#define WS_H      (WS_P1 + 9437184)          // bf16[3072][768]       4.7 MB
#define WS_WDT    (WS_H + 4718592)           // bf16[8][1024][768]    12.6 MB
#define WS_WDST   (WS_WDT + 12582912)        // bf16[1024][768]
#define WS_WGUT   (WS_WDST + 1572864)        // bf16[8][1536][1024]   25.2 MB
#define WS_WGUST  (WS_WGUT + 25165824)       // bf16[1536][1024]      3.1 MB
#define WS_Y      WS_WGUT                    // f32[3072][1024] overlaps consumed Wgut
// total ~58.8 MB

__device__ __forceinline__ u16 f2bf(float x) {
    unsigned int u = __float_as_uint(x);
    u += 0x7fffu + ((u >> 16) & 1u);
    return (u16)(u >> 16);
}
__device__ __forceinline__ float bf2f(u16 h) {
    return __uint_as_float(((unsigned int)h) << 16);
}

// async global->LDS, 16B per lane. LDS dest = wave-uniform base + lane*16.
__device__ __forceinline__ void async16(const void* g, void* s) {
    __builtin_amdgcn_global_load_lds(
        (const __attribute__((address_space(1))) unsigned int*)g,
        (__attribute__((address_space(3))) unsigned int*)s, 16, 0, 0);
}

#define PIN()   __builtin_amdgcn_sched_barrier(0)
#define BAR()   do { PIN(); __builtin_amdgcn_s_barrier(); PIN(); } while (0)
#define WAIT6() do { asm volatile("s_waitcnt vmcnt(6)" ::: "memory"); PIN(); } while (0)
#define WAIT0() do { asm volatile("s_waitcnt vmcnt(0)" ::: "memory"); PIN(); } while (0)

// ---------------- router ----------------
__global__ __launch_bounds__(256) void router_kernel(
    const float* __restrict__ X, const float* __restrict__ Wr,
    const float* __restrict__ bias, int* __restrict__ sel, float* __restrict__ wts)
{
    int t = blockIdx.x * 4 + (threadIdx.x >> 6);
    int lane = threadIdx.x & 63;
    if (t >= T_TOK) return;
    const float* xrow = X + (size_t)t * D_DIM;
    float acc[E_NUM];
#pragma unroll
    for (int e = 0; e < E_NUM; ++e) acc[e] = 0.f;
    for (int d = lane; d < D_DIM; d += 64) {
        float xv = xrow[d];
        const float4* wr = (const float4*)(Wr + (size_t)d * E_NUM);
        float4 w0 = wr[0], w1 = wr[1];
        acc[0] += xv * w0.x; acc[1] += xv * w0.y; acc[2] += xv * w0.z; acc[3] += xv * w0.w;
        acc[4] += xv * w1.x; acc[5] += xv * w1.y; acc[6] += xv * w1.z; acc[7] += xv * w1.w;
    }
#pragma unroll
    for (int e = 0; e < E_NUM; ++e)
#pragma unroll
        for (int off = 32; off > 0; off >>= 1)
            acc[e] += __shfl_xor(acc[e], off);
    if (lane == 0) {
        float s[E_NUM], b[E_NUM];
#pragma unroll
        for (int e = 0; e < E_NUM; ++e) {
            s[e] = 1.f / (1.f + expf(-acc[e]));
            b[e] = s[e] + bias[e];
        }
        int i1 = 0; float b1 = b[0];
#pragma unroll
        for (int e = 1; e < E_NUM; ++e) if (b[e] > b1) { b1 = b[e]; i1 = e; }
        int i2 = -1; float b2 = -INFINITY;
#pragma unroll
        for (int e = 0; e < E_NUM; ++e) {
            if (e == i1) continue;
            if (b[e] > b2) { b2 = b[e]; i2 = e; }
        }
        float s1 = s[i1], s2 = s[i2];
        float denom = s1 + s2 + 1e-20f;
        sel[2 * t] = i1; sel[2 * t + 1] = i2;
        wts[2 * t] = s1 / denom; wts[2 * t + 1] = s2 / denom;
    }
}

// ---------------- dispatch ----------------
__global__ __launch_bounds__(512) void dispatch_kernel(
    const int* __restrict__ sel, int* __restrict__ bucket,
    int* __restrict__ counts, int* __restrict__ offs, int* __restrict__ pos)
{
    __shared__ int soffs[E_NUM + 1];
    int e = threadIdx.x >> 6;
    int lane = threadIdx.x & 63;
    int running = 0;
    for (int base = 0; base < N_SLOTS; base += 64) {
        int slot = base + lane;
        bool mine = (sel[slot] == e);
        unsigned long long mask = __ballot(mine);
        if (mine) {
            int rank = running + __popcll(mask & ((1ull << lane) - 1ull));
            bucket[e * T_TOK + rank] = slot;
        }
        running += __popcll(mask);
    }
    if (lane == 0) counts[e] = running;
    __syncthreads();
    if (threadIdx.x == 0) {
        int o = 0;
        for (int k = 0; k < E_NUM; ++k) { soffs[k] = o; offs[k] = o; o += counts[k]; }
        soffs[E_NUM] = o; offs[E_NUM] = o;
    }
    __syncthreads();
    int base_off = soffs[e];
    for (int r = lane; r < running; r += 64)
        pos[bucket[e * T_TOK + r]] = base_off + r;
}

// ---------------- prep: transpose + cvt weights to bf16 [N][K] ----------------
__global__ __launch_bounds__(256) void transpose_cvt(
    const float* __restrict__ Wg, const float* __restrict__ Wu,
    const float* __restrict__ Wd, const float* __restrict__ Wgs,
    const float* __restrict__ Wus, const float* __restrict__ Wds,
    u16* __restrict__ Wgut, u16* __restrict__ Wdt,
    u16* __restrict__ Wgust, u16* __restrict__ Wdst)
{
    int z = blockIdx.z;
    const float* src; u16* dst; int R, C;
    if (z < 8)       { src = Wg + (size_t)z * D_DIM * F_DIM;        dst = Wgut + (size_t)z * 1536 * D_DIM;               R = D_DIM; C = F_DIM; }
    else if (z < 16) { int e = z - 8;  src = Wu + (size_t)e * D_DIM * F_DIM; dst = Wgut + (size_t)e * 1536 * D_DIM + (size_t)F_DIM * D_DIM; R = D_DIM; C = F_DIM; }
    else if (z < 24) { int e = z - 16; src = Wd + (size_t)e * F_DIM * D_DIM; dst = Wdt + (size_t)e * D_DIM * F_DIM;      R = F_DIM; C = D_DIM; }
    else if (z == 24){ src = Wgs; dst = Wgust;                      R = D_DIM; C = F_DIM; }
    else if (z == 25){ src = Wus; dst = Wgust + (size_t)F_DIM * D_DIM; R = D_DIM; C = F_DIM; }
    else             { src = Wds; dst = Wdst;                       R = F_DIM; C = D_DIM; }
    int c0 = blockIdx.x * 64, r0 = blockIdx.y * 64;
    if (c0 >= C || r0 >= R) return;

    __shared__ u16 tile[64][72];
    int t = threadIdx.x;
    int rr = t >> 4, cq = (t & 15) * 4;
#pragma unroll
    for (int i = 0; i < 4; ++i) {
        int rl = rr + 16 * i;
        float4 v = *(const float4*)(src + (size_t)(r0 + rl) * C + c0 + cq);
        tile[cq + 0][rl] = f2bf(v.x);
        tile[cq + 1][rl] = f2bf(v.y);
        tile[cq + 2][rl] = f2bf(v.z);
        tile[cq + 3][rl] = f2bf(v.w);
    }
    __syncthreads();
#pragma unroll
    for (int j = 0; j < 2; ++j) {
        int idx = t + 256 * j;
        int cc = idx >> 3, q = idx & 7;
        *(uint4*)(dst + (size_t)(c0 + cc) * R + r0 + q * 8) = *(const uint4*)&tile[cc][q * 8];
    }
}

// ---------------- X -> bf16 (plain layout) ----------------
__global__ __launch_bounds__(256) void xcvt_kernel(
    const float* __restrict__ X, u16* __restrict__ Xb)
{
    int i8 = (blockIdx.x * 256 + threadIdx.x) * 8;
    float4 v0 = *(const float4*)(X + i8);
    float4 v1 = *(const float4*)(X + i8 + 4);
    u16 o[8];
    o[0] = f2bf(v0.x); o[1] = f2bf(v0.y); o[2] = f2bf(v0.z); o[3] = f2bf(v0.w);
    o[4] = f2bf(v1.x); o[5] = f2bf(v1.y); o[6] = f2bf(v1.z); o[7] = f2bf(v1.w);
    *(uint4*)(Xb + i8) = *(const uint4*)o;
}

// ================= proj1: P1 = Xb @ Wgut^T  (BM=128,BN=64,BK=64) =================
// grid 3456: c=i&7, m=i>>3, y=m&15, phi=m>>4; panel=phi*8+c (0..215); unit=panel/24, x=panel%24
__global__ __launch_bounds__(256, 3) void proj1(
    const u16* __restrict__ Xb, const u16* __restrict__ Wgut, const u16* __restrict__ Wgust,
    u16* __restrict__ P1,
    const int* __restrict__ bucket, const int* __restrict__ counts, const int* __restrict__ offs)
{
    const int i = blockIdx.x;
    const int cxcd = i & 7, m = i >> 3;
    const int y = m & 15, phi = m >> 4;
    const int panel = phi * 8 + cxcd;
    const int unit = panel / 24, x = panel - unit * 24;

    int nrows, rbase; const u16* Wt;
    if (unit < E_NUM) {
        nrows = counts[unit]; rbase = offs[unit];
        Wt = Wgut + (size_t)unit * 1536 * D_DIM;
    } else {
        nrows = T_TOK; rbase = N_SLOTS; Wt = Wgust;
    }
    const int row0 = y * 128, n0 = x * 64;
    if (row0 >= nrows) return;

    __shared__ u16 smem[2][192 * 64];   // A rows 0..127, B rows 128..191; row stride 64 u16

    const int t = threadIdx.x;
    const int wv = t >> 6, lane = t & 63, l15 = lane & 15, lg = lane >> 4;
    const int wm = wv >> 1, wn = wv & 1;
    const int rl = lane >> 3, cch = lane & 7;

    // precompute per-lane global sources (XOR-swizzled chunk within 128B row)
    const u16* srcA[4];
#pragma unroll
    for (int j = 0; j < 4; ++j) {
        int arow = wv * 32 + j * 8 + rl;                 // LDS A row 0..127
        int grow = min(row0 + arow, nrows - 1);
        if (unit < E_NUM) grow = bucket[unit * T_TOK + grow] >> 1;
        srcA[j] = Xb + (size_t)grow * D_DIM + (cch ^ (arow & 7)) * 8;
    }
    const u16* srcB[2];
#pragma unroll
    for (int j = 0; j < 2; ++j) {
        int brow = wv * 16 + j * 8 + rl;                 // 0..63
        srcB[j] = Wt + (size_t)(n0 + brow) * D_DIM + (cch ^ (brow & 7)) * 8;
    }

    f32x4 acc[4][2];
    const f32x4 z4 = {0.f, 0.f, 0.f, 0.f};
#pragma unroll
    for (int ri = 0; ri < 4; ++ri)
#pragma unroll
        for (int ci = 0; ci < 2; ++ci) acc[ri][ci] = z4;

#define STAGE1(buf, kt) do { \
    _Pragma("unroll") \
    for (int j = 0; j < 4; ++j) \
        async16(srcA[j] + (kt), &smem[buf][(wv * 32 + j * 8) * 64]); \
    _Pragma("unroll") \
    for (int j = 0; j < 2; ++j) \
        async16(srcB[j] + (kt), &smem[buf][(128 + wv * 16 + j * 8) * 64]); \
} while (0)

#define COMP1(buf) do { \
    bf16x8 av[4][2], bv[2][2]; \
    _Pragma("unroll") \
    for (int ri = 0; ri < 4; ++ri) { \
        int row = wm * 64 + ri * 16 + l15; \
        _Pragma("unroll") \
        for (int kk = 0; kk < 2; ++kk) { \
            int ch = ((kk << 2) | lg) ^ (row & 7); \
            av[ri][kk] = *(const bf16x8*)&smem[buf][row * 64 + ch * 8]; \
        } \
    } \
    _Pragma("unroll") \
    for (int ci = 0; ci < 2; ++ci) { \
        int br = wn * 32 + ci * 16 + l15; \
        _Pragma("unroll") \
        for (int kk = 0; kk < 2; ++kk) { \
            int ch = ((kk << 2) | lg) ^ (br & 7); \
            bv[ci][kk] = *(const bf16x8*)&smem[buf][(128 + br) * 64 + ch * 8]; \
        } \
    } \
    _Pragma("unroll") \
    for (int kk = 0; kk < 2; ++kk) \
        _Pragma("unroll") \
        for (int ri = 0; ri < 4; ++ri) \
            _Pragma("unroll") \
            for (int ci = 0; ci < 2; ++ci) \
                acc[ri][ci] = __builtin_amdgcn_mfma_f32_16x16x32_bf16( \
                    av[ri][kk], bv[ci][kk], acc[ri][ci], 0, 0, 0); \
} while (0)

    STAGE1(0, 0);
    for (int tt = 0; tt < 16; tt += 2) {
        STAGE1(1, (tt + 1) * 64);
        WAIT6();
        BAR();
        COMP1(0);
        BAR();
        if (tt + 2 < 16) { STAGE1(0, (tt + 2) * 64); WAIT6(); }
        else             { WAIT0(); }
        BAR();
        COMP1(1);
        BAR();
    }
#undef STAGE1
#undef COMP1

#pragma unroll
    for (int ri = 0; ri < 4; ++ri)
#pragma unroll
        for (int ci = 0; ci < 2; ++ci) {
            int n = n0 + wn * 32 + ci * 16 + l15;
#pragma unroll
            for (int r = 0; r < 4; ++r) {
                int row = row0 + wm * 64 + ri * 16 + lg * 4 + r;
                if (row >= nrows) continue;
                P1[(size_t)(rbase + row) * 1536 + n] = f2bf(acc[ri][ci][r]);
            }
        }
}

// ---------------- glu: H = silu(P1[:, :768]) * P1[:, 768:] ----------------
__global__ __launch_bounds__(256) void glu_kernel(
    const u16* __restrict__ P1, u16* __restrict__ H)
{
    int i8 = (blockIdx.x * 256 + threadIdx.x) * 8;       // over 3072*768
    int r = i8 / F_DIM, f = i8 - r * F_DIM;
    bf16x8 g8 = *(const bf16x8*)(P1 + (size_t)r * 1536 + f);
    bf16x8 u8 = *(const bf16x8*)(P1 + (size_t)r * 1536 + F_DIM + f);
    u16 hv[8];
#pragma unroll
    for (int j = 0; j < 8; ++j) {
        float gv = bf2f((u16)g8[j]);
        float uv = bf2f((u16)u8[j]);
        hv[j] = f2bf(gv / (1.f + __expf(-gv)) * uv);
    }
    *(uint4*)(H + (size_t)r * F_DIM + f) = *(const uint4*)hv;
}

// ================= proj2: Y = H @ Wdt^T  (BM=128,BN=64,BK=64,K=768) =================
// grid 2304: c=i&7, m=i>>3, y=m&15, phi=m>>4; panel=phi*8+c (0..143); unit=panel/16, x=panel%16
__global__ __launch_bounds__(256, 3) void proj2(
    const u16* __restrict__ H, const u16* __restrict__ Wdt, const u16* __restrict__ Wdst,
    float* __restrict__ Y,
    const int* __restrict__ counts, const int* __restrict__ offs)
{
    const int i = blockIdx.x;
    const int cxcd = i & 7, m = i >> 3;
    const int y = m & 15, phi = m >> 4;
    const int panel = phi * 8 + cxcd;
    const int unit = panel >> 4, x = panel & 15;

    int nrows, rbase; const u16* Wt;
    if (unit < E_NUM) {
        nrows = counts[unit]; rbase = offs[unit];
        Wt = Wdt + (size_t)unit * D_DIM * F_DIM;
    } else {
        nrows = T_TOK; rbase = N_SLOTS; Wt = Wdst;
    }
    const int row0 = y * 128, n0 = x * 64;
    if (row0 >= nrows) return;

    __shared__ u16 smem[2][192 * 64];

    const int t = threadIdx.x;
    const int wv = t >> 6, lane = t & 63, l15 = lane & 15, lg = lane >> 4;
    const int wm = wv >> 1, wn = wv & 1;
    const int rl = lane >> 3, cch = lane & 7;

    const u16* srcA[4];
#pragma unroll
    for (int j = 0; j < 4; ++j) {
        int arow = wv * 32 + j * 8 + rl;
        int grow = rbase + min(row0 + arow, nrows - 1);
        srcA[j] = H + (size_t)grow * F_DIM + (cch ^ (arow & 7)) * 8;
    }
    const u16* srcB[2];
#pragma unroll
    for (int j = 0; j < 2; ++j) {
        int brow = wv * 16 + j * 8 + rl;
        srcB[j] = Wt + (size_t)(n0 + brow) * F_DIM + (cch ^ (brow & 7)) * 8;
    }

    f32x4 acc[4][2];
    const f32x4 z4 = {0.f, 0.f, 0.f, 0.f};
#pragma unroll
    for (int ri = 0; ri < 4; ++ri)
#pragma unroll
        for (int ci = 0; ci < 2; ++ci) acc[ri][ci] = z4;

#define STAGE2(buf, kt) do { \
    _Pragma("unroll") \
    for (int j = 0; j < 4; ++j) \
        async16(srcA[j] + (kt), &smem[buf][(wv * 32 + j * 8) * 64]); \
    _Pragma("unroll") \
    for (int j = 0; j < 2; ++j) \
        async16(srcB[j] + (kt), &smem[buf][(128 + wv * 16 + j * 8) * 64]); \
} while (0)

#define COMP2(buf) do { \
    bf16x8 av[4][2], bv[2][2]; \
    _Pragma("unroll") \
    for (int ri = 0; ri < 4; ++ri) { \
        int row = wm * 64 + ri * 16 + l15; \
        _Pragma("unroll") \
        for (int kk = 0; kk < 2; ++kk) { \
            int ch = ((kk << 2) | lg) ^ (row & 7); \
            av[ri][kk] = *(const bf16x8*)&smem[buf][row * 64 + ch * 8]; \
        } \
    } \
    _Pragma("unroll") \
    for (int ci = 0; ci < 2; ++ci) { \
        int br = wn * 32 + ci * 16 + l15; \
        _Pragma("unroll") \
        for (int kk = 0; kk < 2; ++kk) { \
            int ch = ((kk << 2) | lg) ^ (br & 7); \
            bv[ci][kk] = *(const bf16x8*)&smem[buf][(128 + br) * 64 + ch * 8]; \
        } \
    } \
    _Pragma("unroll") \
    for (int kk = 0; kk < 2; ++kk) \
        _Pragma("unroll") \
        for (int ri = 0; ri < 4; ++ri) \
            _Pragma("unroll") \
            for (int ci = 0; ci < 2; ++ci) \
                acc[ri][ci] = __builtin_amdgcn_mfma_f32_16x16x32_bf16( \
                    av[ri][kk], bv[ci][kk], acc[ri][ci], 0, 0, 0); \
} while (0)

    STAGE2(0, 0);
    for (int tt = 0; tt < 12; tt += 2) {
        STAGE2(1, (tt + 1) * 64);
        WAIT6();
        BAR();
        COMP2(0);
        BAR();
        if (tt + 2 < 12) { STAGE2(0, (tt + 2) * 64); WAIT6(); }
        else             { WAIT0(); }
        BAR();
        COMP2(1);
        BAR();
    }
#undef STAGE2
#undef COMP2

#pragma unroll
    for (int ri = 0; ri < 4; ++ri)
#pragma unroll
        for (int ci = 0; ci < 2; ++ci) {
            int n = n0 + wn * 32 + ci * 16 + l15;
#pragma unroll
            for (int r = 0; r < 4; ++r) {
                int row = row0 + wm * 64 + ri * 16 + lg * 4 + r;
                if (row >= nrows) continue;
                Y[(size_t)(rbase + row) * D_DIM + n] = acc[ri][ci][r];
            }
        }
}

// ---------------- combine ----------------
__global__ __launch_bounds__(256) void combine_kernel(
    const float* __restrict__ Y, const int* __restrict__ pos,
    const float* __restrict__ wts, float* __restrict__ out)
{
    int t = blockIdx.x;
    int d = threadIdx.x * 4;
    int p0 = pos[2 * t], p1 = pos[2 * t + 1];
    float w0 = wts[2 * t], w1 = wts[2 * t + 1];
    float4 a = *(const float4*)(Y + (size_t)(N_SLOTS + t) * D_DIM + d);
    float4 b = *(const float4*)(Y + (size_t)p0 * D_DIM + d);
    float4 cc = *(const float4*)(Y + (size_t)p1 * D_DIM + d);
    float4 o;
    o.x = a.x + w0 * b.x + w1 * cc.x;
    o.y = a.y + w0 * b.y + w1 * cc.y;
    o.z = a.z + w0 * b.z + w1 * cc.z;
    o.w = a.w + w0 * b.w + w1 * cc.w;
    *(float4*)(out + (size_t)t * D_DIM + d) = o;
}

extern "C" void kernel_launch(void* const* d_in, const int* in_sizes, int n_in,
                              void* d_out, int out_size, void* d_ws, size_t ws_size,
                              hipStream_t stream) {
    const float* X    = (const float*)d_in[0];
    const float* Wr   = (const float*)d_in[1];
    const float* bias = (const float*)d_in[2];
    const float* Wg   = (const float*)d_in[3];
    const float* Wu   = (const float*)d_in[4];
    const float* Wd   = (const float*)d_in[5];
    const float* Wgs  = (const float*)d_in[6];
    const float* Wus  = (const float*)d_in[7];
    const float* Wds  = (const float*)d_in[8];
    float* out = (float*)d_out;

    char* ws = (char*)d_ws;
    int*   sel    = (int*)(ws + WS_SEL);
    float* wtsv   = (float*)(ws + WS_WTS);
    int*   bucket = (int*)(ws + WS_BUCKET);
    int*   counts = (int*)(ws + WS_COUNTS);
    int*   offs   = (int*)(ws + WS_OFFS);
    int*   pos    = (int*)(ws + WS_POS);
    u16*   Xb     = (u16*)(ws + WS_XB);
    u16*   P1     = (u16*)(ws + WS_P1);
    u16*   H      = (u16*)(ws + WS_H);
    u16*   Wdt    = (u16*)(ws + WS_WDT);
    u16*   Wdst   = (u16*)(ws + WS_WDST);
    u16*   Wgut   = (u16*)(ws + WS_WGUT);
    u16*   Wgust  = (u16*)(ws + WS_WGUST);
    float* Y      = (float*)(ws + WS_Y);

    transpose_cvt<<<dim3(16, 16, 27), 256, 0, stream>>>(
        Wg, Wu, Wd, Wgs, Wus, Wds, Wgut, Wdt, Wgust, Wdst);
    xcvt_kernel<<<T_TOK * D_DIM / 8 / 256, 256, 0, stream>>>(X, Xb);
    router_kernel<<<256, 256, 0, stream>>>(X, Wr, bias, sel, wtsv);
    dispatch_kernel<<<1, 512, 0, stream>>>(sel, bucket, counts, offs, pos);

    proj1<<<3456, 256, 0, stream>>>(Xb, Wgut, Wgust, P1, bucket, counts, offs);
    glu_kernel<<<3072 * F_DIM / 8 / 256, 256, 0, stream>>>(P1, H);
    proj2<<<2304, 256, 0, stream>>>(H, Wdt, Wdst, Y, counts, offs);
    combine_kernel<<<T_TOK, 256, 0, stream>>>(Y, pos, wtsv, out);
}

// Round 7
// 85.309 us; speedup vs baseline: 4.6469x; 1.1692x over previous
//
#include <hip/hip_runtime.h>
#include <hip/hip_bf16.h>
#include <math.h>

#define T_TOK   1024
#define D_DIM   1024
#define E_NUM   8
#define F_DIM   768
#define N_SLOTS 2048

typedef unsigned short u16;
typedef __attribute__((ext_vector_type(8))) short bf16x8;
typedef __attribute__((ext_vector_type(4))) float f32x4;

// ---- workspace layout (byte offsets) ----
#define WS_SEL    0
#define WS_WTS    8192
#define WS_BUCKET 16384
#define WS_COUNTS 49152
#define WS_OFFS   49216
#define WS_POS    49280
#define WS_XB     65536                      // bf16[1024][1024]      2 MB
#define WS_H      (WS_XB + 2097152)          // bf16[3072][768]       4.7 MB
#define WS_WDT    (WS_H + 4718592)           // bf16[8][1024][768]    12.6 MB
#define WS_WDST   (WS_WDT + 12582912)        // bf16[1024][768]       1.6 MB
#define WS_WGUT   (WS_WDST + 1572864)        // bf16[8][1536][1024]   25.2 MB
#define WS_WGUST  (WS_WGUT + 25165824)       // bf16[1536][1024]      3.1 MB
#define WS_Y      WS_WGUT                    // f32[3072][1024] overlaps consumed Wgut
// total ~49.3 MB

__device__ __forceinline__ u16 f2bf(float x) {
    unsigned int u = __float_as_uint(x);
    u += 0x7fffu + ((u >> 16) & 1u);
    return (u16)(u >> 16);
}
__device__ __forceinline__ float bf2f(u16 h) {
    return __uint_as_float(((unsigned int)h) << 16);
}

// async global->LDS, 16B per lane. LDS dest = wave-uniform base + lane*16.
__device__ __forceinline__ void async16(const void* g, void* s) {
    __builtin_amdgcn_global_load_lds(
        (const __attribute__((address_space(1))) unsigned int*)g,
        (__attribute__((address_space(3))) unsigned int*)s, 16, 0, 0);
}

#define PIN()   __builtin_amdgcn_sched_barrier(0)
#define BAR()   do { PIN(); __builtin_amdgcn_s_barrier(); PIN(); } while (0)
#define WAIT6() do { asm volatile("s_waitcnt vmcnt(6)" ::: "memory"); PIN(); } while (0)
#define WAIT0() do { asm volatile("s_waitcnt vmcnt(0)" ::: "memory"); PIN(); } while (0)

// ---------------- xrouter: bf16-convert X row + router top-2 (one wave per token) ----------------
__global__ __launch_bounds__(256) void xrouter_kernel(
    const float* __restrict__ X, const float* __restrict__ Wr,
    const float* __restrict__ bias, u16* __restrict__ Xb,
    int* __restrict__ sel, float* __restrict__ wts)
{
    int t = blockIdx.x * 4 + (threadIdx.x >> 6);
    int lane = threadIdx.x & 63;
    const float* xrow = X + (size_t)t * D_DIM;
    u16* brow = Xb + (size_t)t * D_DIM;
    float acc[E_NUM];
#pragma unroll
    for (int e = 0; e < E_NUM; ++e) acc[e] = 0.f;
#pragma unroll
    for (int q = 0; q < 4; ++q) {
        int d = q * 256 + lane * 4;
        float4 v = *(const float4*)(xrow + d);
        ushort4 o;
        o.x = f2bf(v.x); o.y = f2bf(v.y); o.z = f2bf(v.z); o.w = f2bf(v.w);
        *(ushort4*)(brow + d) = o;
        const float xv[4] = {v.x, v.y, v.z, v.w};
#pragma unroll
        for (int jj = 0; jj < 4; ++jj) {
            const float4* wr = (const float4*)(Wr + (size_t)(d + jj) * E_NUM);
            float4 w0 = wr[0], w1 = wr[1];
            acc[0] += xv[jj] * w0.x; acc[1] += xv[jj] * w0.y;
            acc[2] += xv[jj] * w0.z; acc[3] += xv[jj] * w0.w;
            acc[4] += xv[jj] * w1.x; acc[5] += xv[jj] * w1.y;
            acc[6] += xv[jj] * w1.z; acc[7] += xv[jj] * w1.w;
        }
    }
#pragma unroll
    for (int e = 0; e < E_NUM; ++e)
#pragma unroll
        for (int off = 32; off > 0; off >>= 1)
            acc[e] += __shfl_xor(acc[e], off);
    if (lane == 0) {
        float s[E_NUM], b[E_NUM];
#pragma unroll
        for (int e = 0; e < E_NUM; ++e) {
            s[e] = 1.f / (1.f + expf(-acc[e]));
            b[e] = s[e] + bias[e];
        }
        int i1 = 0; float b1 = b[0];
#pragma unroll
        for (int e = 1; e < E_NUM; ++e) if (b[e] > b1) { b1 = b[e]; i1 = e; }
        int i2 = -1; float b2 = -INFINITY;
#pragma unroll
        for (int e = 0; e < E_NUM; ++e) {
            if (e == i1) continue;
            if (b[e] > b2) { b2 = b[e]; i2 = e; }
        }
        float s1 = s[i1], s2 = s[i2];
        float denom = s1 + s2 + 1e-20f;
        sel[2 * t] = i1; sel[2 * t + 1] = i2;
        wts[2 * t] = s1 / denom; wts[2 * t + 1] = s2 / denom;
    }
}

// ---------------- dispatch ----------------
__global__ __launch_bounds__(512) void dispatch_kernel(
    const int* __restrict__ sel, int* __restrict__ bucket,
    int* __restrict__ counts, int* __restrict__ offs, int* __restrict__ pos)
{
    __shared__ int soffs[E_NUM + 1];
    int e = threadIdx.x >> 6;
    int lane = threadIdx.x & 63;
    int running = 0;
    for (int base = 0; base < N_SLOTS; base += 64) {
        int slot = base + lane;
        bool mine = (sel[slot] == e);
        unsigned long long mask = __ballot(mine);
        if (mine) {
            int rank = running + __popcll(mask & ((1ull << lane) - 1ull));
            bucket[e * T_TOK + rank] = slot;
        }
        running += __popcll(mask);
    }
    if (lane == 0) counts[e] = running;
    __syncthreads();
    if (threadIdx.x == 0) {
        int o = 0;
        for (int k = 0; k < E_NUM; ++k) { soffs[k] = o; offs[k] = o; o += counts[k]; }
        soffs[E_NUM] = o; offs[E_NUM] = o;
    }
    __syncthreads();
    int base_off = soffs[e];
    for (int r = lane; r < running; r += 64)
        pos[bucket[e * T_TOK + r]] = base_off + r;
}

// ---------------- prep: transpose + cvt weights to bf16 [N][K] ----------------
__global__ __launch_bounds__(256) void transpose_cvt(
    const float* __restrict__ Wg, const float* __restrict__ Wu,
    const float* __restrict__ Wd, const float* __restrict__ Wgs,
    const float* __restrict__ Wus, const float* __restrict__ Wds,
    u16* __restrict__ Wgut, u16* __restrict__ Wdt,
    u16* __restrict__ Wgust, u16* __restrict__ Wdst)
{
    int z = blockIdx.z;
    const float* src; u16* dst; int R, C;
    if (z < 8)       { src = Wg + (size_t)z * D_DIM * F_DIM;        dst = Wgut + (size_t)z * 1536 * D_DIM;               R = D_DIM; C = F_DIM; }
    else if (z < 16) { int e = z - 8;  src = Wu + (size_t)e * D_DIM * F_DIM; dst = Wgut + (size_t)e * 1536 * D_DIM + (size_t)F_DIM * D_DIM; R = D_DIM; C = F_DIM; }
    else if (z < 24) { int e = z - 16; src = Wd + (size_t)e * F_DIM * D_DIM; dst = Wdt + (size_t)e * D_DIM * F_DIM;      R = F_DIM; C = D_DIM; }
    else if (z == 24){ src = Wgs; dst = Wgust;                      R = D_DIM; C = F_DIM; }
    else if (z == 25){ src = Wus; dst = Wgust + (size_t)F_DIM * D_DIM; R = D_DIM; C = F_DIM; }
    else             { src = Wds; dst = Wdst;                       R = F_DIM; C = D_DIM; }
    int c0 = blockIdx.x * 64, r0 = blockIdx.y * 64;
    if (c0 >= C || r0 >= R) return;

    __shared__ u16 tile[64][72];
    int t = threadIdx.x;
    int rr = t >> 4, cq = (t & 15) * 4;
#pragma unroll
    for (int i = 0; i < 4; ++i) {
        int rl = rr + 16 * i;
        float4 v = *(const float4*)(src + (size_t)(r0 + rl) * C + c0 + cq);
        tile[cq + 0][rl] = f2bf(v.x);
        tile[cq + 1][rl] = f2bf(v.y);
        tile[cq + 2][rl] = f2bf(v.z);
        tile[cq + 3][rl] = f2bf(v.w);
    }
    __syncthreads();
#pragma unroll
    for (int j = 0; j < 2; ++j) {
        int idx = t + 256 * j;
        int cc = idx >> 3, q = idx & 7;
        *(uint4*)(dst + (size_t)(c0 + cc) * R + r0 + q * 8) = *(const uint4*)&tile[cc][q * 8];
    }
}

// ================= proj1: H = silu(Xb@Wg^T) * (Xb@Wu^T)  (BM=64, gate64+up64, BK=64) =================
// grid 3584: c=i&7(XCD), m=i>>3, y=m&31, phi=m>>5; panel=phi*8+c (0..111, skip>=108);
// unit=panel/12 (0..8), x=panel%12 (64-col F panel)
__global__ __launch_bounds__(256, 3) void proj1(
    const u16* __restrict__ Xb, const u16* __restrict__ Wgut, const u16* __restrict__ Wgust,
    u16* __restrict__ H,
    const int* __restrict__ bucket, const int* __restrict__ counts, const int* __restrict__ offs)
{
    const int i = blockIdx.x;
    const int cxcd = i & 7, m = i >> 3;
    const int y = m & 31, phi = m >> 5;
    const int panel = phi * 8 + cxcd;
    if (panel >= 108) return;
    const int unit = panel / 12, x = panel - unit * 12;

    int nrows, rbase; const u16* Wt;
    if (unit < E_NUM) {
        nrows = counts[unit]; rbase = offs[unit];
        Wt = Wgut + (size_t)unit * 1536 * D_DIM;
    } else {
        nrows = T_TOK; rbase = N_SLOTS; Wt = Wgust;
    }
    const int row0 = y * 64;
    if (row0 >= nrows) return;

    // LDS rows: 0..63 A, 64..127 gate B, 128..191 up B; row = 64 u16 (128B, 8 chunks)
    __shared__ u16 smem[2][192 * 64];

    const int t = threadIdx.x;
    const int wv = t >> 6, lane = t & 63, l15 = lane & 15, lg = lane >> 4;
    const int wm = wv >> 1, wn = wv & 1;
    const int rl = lane >> 3, cch = lane & 7;

    const u16* srcA[2];
#pragma unroll
    for (int j = 0; j < 2; ++j) {
        int arow = wv * 16 + j * 8 + rl;                 // 0..63
        int grow = min(row0 + arow, nrows - 1);
        if (unit < E_NUM) grow = bucket[unit * T_TOK + grow] >> 1;
        srcA[j] = Xb + (size_t)grow * D_DIM + (cch ^ (arow & 7)) * 8;
    }
    const u16* srcB[4];
#pragma unroll
    for (int j = 0; j < 4; ++j) {
        int br = wv * 32 + j * 8 + rl;                   // 0..127 (0..63 gate, 64..127 up)
        size_t n = (size_t)(br >> 6) * F_DIM + x * 64 + (br & 63);
        srcB[j] = Wt + n * D_DIM + (cch ^ (br & 7)) * 8;
    }

    f32x4 accg[2][2], accu[2][2];
    const f32x4 z4 = {0.f, 0.f, 0.f, 0.f};
#pragma unroll
    for (int ri = 0; ri < 2; ++ri)
#pragma unroll
        for (int ci = 0; ci < 2; ++ci) { accg[ri][ci] = z4; accu[ri][ci] = z4; }

#define STAGE1(buf, kt) do { \
    _Pragma("unroll") \
    for (int j = 0; j < 2; ++j) \
        async16(srcA[j] + (kt), &smem[buf][(wv * 16 + j * 8) * 64]); \
    _Pragma("unroll") \
    for (int j = 0; j < 4; ++j) \
        async16(srcB[j] + (kt), &smem[buf][(64 + wv * 32 + j * 8) * 64]); \
} while (0)

#define COMP1(buf) do { \
    bf16x8 av[2][2], bg[2][2], bu[2][2]; \
    _Pragma("unroll") \
    for (int ri = 0; ri < 2; ++ri) { \
        int row = wm * 32 + ri * 16 + l15; \
        _Pragma("unroll") \
        for (int kk = 0; kk < 2; ++kk) { \
            int ch = ((kk << 2) | lg) ^ (row & 7); \
            av[ri][kk] = *(const bf16x8*)&smem[buf][row * 64 + ch * 8]; \
        } \
    } \
    _Pragma("unroll") \
    for (int ci = 0; ci < 2; ++ci) { \
        int br = wn * 32 + ci * 16 + l15; \
        _Pragma("unroll") \
        for (int kk = 0; kk < 2; ++kk) { \
            int ch = ((kk << 2) | lg) ^ (br & 7); \
            bg[ci][kk] = *(const bf16x8*)&smem[buf][(64 + br) * 64 + ch * 8]; \
            bu[ci][kk] = *(const bf16x8*)&smem[buf][(128 + br) * 64 + ch * 8]; \
        } \
    } \
    _Pragma("unroll") \
    for (int kk = 0; kk < 2; ++kk) \
        _Pragma("unroll") \
        for (int ri = 0; ri < 2; ++ri) \
            _Pragma("unroll") \
            for (int ci = 0; ci < 2; ++ci) { \
                accg[ri][ci] = __builtin_amdgcn_mfma_f32_16x16x32_bf16( \
                    av[ri][kk], bg[ci][kk], accg[ri][ci], 0, 0, 0); \
                accu[ri][ci] = __builtin_amdgcn_mfma_f32_16x16x32_bf16( \
                    av[ri][kk], bu[ci][kk], accu[ri][ci], 0, 0, 0); \
            } \
} while (0)

    STAGE1(0, 0);
    for (int tt = 0; tt < 16; tt += 2) {
        STAGE1(1, (tt + 1) * 64);
        WAIT6();
        BAR();
        COMP1(0);
        BAR();
        if (tt + 2 < 16) { STAGE1(0, (tt + 2) * 64); WAIT6(); }
        else             { WAIT0(); }
        BAR();
        COMP1(1);
        BAR();
    }
#undef STAGE1
#undef COMP1

    // epilogue: fused SiLU-GLU, write H bf16
#pragma unroll
    for (int ri = 0; ri < 2; ++ri)
#pragma unroll
        for (int ci = 0; ci < 2; ++ci) {
            int n = x * 64 + wn * 32 + ci * 16 + l15;
#pragma unroll
            for (int r = 0; r < 4; ++r) {
                int row = row0 + wm * 32 + ri * 16 + lg * 4 + r;
                if (row >= nrows) continue;
                float gv = accg[ri][ci][r];
                float uv = accu[ri][ci][r];
                H[(size_t)(rbase + row) * F_DIM + n] =
                    f2bf(gv / (1.f + __expf(-gv)) * uv);
            }
        }
}

// ================= proj2: Y = H @ Wd^T  (BM=64, BN=128, BK=64, K=768) =================
// grid 2304: c=i&7, m=i>>3, y=m&31, phi=m>>5; panel=phi*8+c (0..71); unit=panel/8, x=panel%8
// wave (wm,wn) covers rows wm*32..+31, cols wn*64..+63  -> full 64x128 tile
__global__ __launch_bounds__(256, 3) void proj2(
    const u16* __restrict__ H, const u16* __restrict__ Wdt, const u16* __restrict__ Wdst,
    float* __restrict__ Y,
    const int* __restrict__ counts, const int* __restrict__ offs)
{
    const int i = blockIdx.x;
    const int cxcd = i & 7, m = i >> 3;
    const int y = m & 31, phi = m >> 5;
    const int panel = phi * 8 + cxcd;
    const int unit = panel >> 3, x = panel & 7;

    int nrows, rbase; const u16* Wt;
    if (unit < E_NUM) {
        nrows = counts[unit]; rbase = offs[unit];
        Wt = Wdt + (size_t)unit * D_DIM * F_DIM;
    } else {
        nrows = T_TOK; rbase = N_SLOTS; Wt = Wdst;
    }
    const int row0 = y * 64, n0 = x * 128;
    if (row0 >= nrows) return;

    // LDS rows: 0..63 A (H), 64..191 B (Wd cols n0..n0+127)
    __shared__ u16 smem[2][192 * 64];

    const int t = threadIdx.x;
    const int wv = t >> 6, lane = t & 63, l15 = lane & 15, lg = lane >> 4;
    const int wm = wv >> 1, wn = wv & 1;
    const int rl = lane >> 3, cch = lane & 7;

    const u16* srcA[2];
#pragma unroll
    for (int j = 0; j < 2; ++j) {
        int arow = wv * 16 + j * 8 + rl;
        int grow = rbase + min(row0 + arow, nrows - 1);
        srcA[j] = H + (size_t)grow * F_DIM + (cch ^ (arow & 7)) * 8;
    }
    const u16* srcB[4];
#pragma unroll
    for (int j = 0; j < 4; ++j) {
        int br = wv * 32 + j * 8 + rl;                   // 0..127
        srcB[j] = Wt + (size_t)(n0 + br) * F_DIM + (cch ^ (br & 7)) * 8;
    }

    f32x4 acc[2][4];
    const f32x4 z4 = {0.f, 0.f, 0.f, 0.f};
#pragma unroll
    for (int ri = 0; ri < 2; ++ri)
#pragma unroll
        for (int ci = 0; ci < 4; ++ci) acc[ri][ci] = z4;

#define STAGE2(buf, kt) do { \
    _Pragma("unroll") \
    for (int j = 0; j < 2; ++j) \
        async16(srcA[j] + (kt), &smem[buf][(wv * 16 + j * 8) * 64]); \
    _Pragma("unroll") \
    for (int j = 0; j < 4; ++j) \
        async16(srcB[j] + (kt), &smem[buf][(64 + wv * 32 + j * 8) * 64]); \
} while (0)

#define COMP2(buf) do { \
    bf16x8 av[2][2], bv[4][2]; \
    _Pragma("unroll") \
    for (int ri = 0; ri < 2; ++ri) { \
        int row = wm * 32 + ri * 16 + l15; \
        _Pragma("unroll") \
        for (int kk = 0; kk < 2; ++kk) { \
            int ch = ((kk << 2) | lg) ^ (row & 7); \
            av[ri][kk] = *(const bf16x8*)&smem[buf][row * 64 + ch * 8]; \
        } \
    } \
    _Pragma("unroll") \
    for (int ci = 0; ci < 4; ++ci) { \
        int br = wn * 64 + ci * 16 + l15; \
        _Pragma("unroll") \
        for (int kk = 0; kk < 2; ++kk) { \
            int ch = ((kk << 2) | lg) ^ (br & 7); \
            bv[ci][kk] = *(const bf16x8*)&smem[buf][(64 + br) * 64 + ch * 8]; \
        } \
    } \
    _Pragma("unroll") \
    for (int kk = 0; kk < 2; ++kk) \
        _Pragma("unroll") \
        for (int ri = 0; ri < 2; ++ri) \
            _Pragma("unroll") \
            for (int ci = 0; ci < 4; ++ci) \
                acc[ri][ci] = __builtin_amdgcn_mfma_f32_16x16x32_bf16( \
                    av[ri][kk], bv[ci][kk], acc[ri][ci], 0, 0, 0); \
} while (0)

    STAGE2(0, 0);
    for (int tt = 0; tt < 12; tt += 2) {
        STAGE2(1, (tt + 1) * 64);
        WAIT6();
        BAR();
        COMP2(0);
        BAR();
        if (tt + 2 < 12) { STAGE2(0, (tt + 2) * 64); WAIT6(); }
        else             { WAIT0(); }
        BAR();
        COMP2(1);
        BAR();
    }
#undef STAGE2
#undef COMP2

#pragma unroll
    for (int ri = 0; ri < 2; ++ri)
#pragma unroll
        for (int ci = 0; ci < 4; ++ci) {
            int n = n0 + wn * 64 + ci * 16 + l15;
#pragma unroll
            for (int r = 0; r < 4; ++r) {
                int row = row0 + wm * 32 + ri * 16 + lg * 4 + r;
                if (row >= nrows) continue;
                Y[(size_t)(rbase + row) * D_DIM + n] = acc[ri][ci][r];
            }
        }
}

// ---------------- combine ----------------
__global__ __launch_bounds__(256) void combine_kernel(
    const float* __restrict__ Y, const int* __restrict__ pos,
    const float* __restrict__ wts, float* __restrict__ out)
{
    int t = blockIdx.x;
    int d = threadIdx.x * 4;
    int p0 = pos[2 * t], p1 = pos[2 * t + 1];
    float w0 = wts[2 * t], w1 = wts[2 * t + 1];
    float4 a = *(const float4*)(Y + (size_t)(N_SLOTS + t) * D_DIM + d);
    float4 b = *(const float4*)(Y + (size_t)p0 * D_DIM + d);
    float4 cc = *(const float4*)(Y + (size_t)p1 * D_DIM + d);
    float4 o;
    o.x = a.x + w0 * b.x + w1 * cc.x;
    o.y = a.y + w0 * b.y + w1 * cc.y;
    o.z = a.z + w0 * b.z + w1 * cc.z;
    o.w = a.w + w0 * b.w + w1 * cc.w;
    *(float4*)(out + (size_t)t * D_DIM + d) = o;
}

extern "C" void kernel_launch(void* const* d_in, const int* in_sizes, int n_in,
                              void* d_out, int out_size, void* d_ws, size_t ws_size,
                              hipStream_t stream) {
    const float* X    = (const float*)d_in[0];
    const float* Wr   = (const float*)d_in[1];
    const float* bias = (const float*)d_in[2];
    const float* Wg   = (const float*)d_in[3];
    const float* Wu   = (const float*)d_in[4];
    const float* Wd   = (const float*)d_in[5];
    const float* Wgs  = (const float*)d_in[6];
    const float* Wus  = (const float*)d_in[7];
    const float* Wds  = (const float*)d_in[8];
    float* out = (float*)d_out;

    char* ws = (char*)d_ws;
    int*   sel    = (int*)(ws + WS_SEL);
    float* wtsv   = (float*)(ws + WS_WTS);
    int*   bucket = (int*)(ws + WS_BUCKET);
    int*   counts = (int*)(ws + WS_COUNTS);
    int*   offs   = (int*)(ws + WS_OFFS);
    int*   pos    = (int*)(ws + WS_POS);
    u16*   Xb     = (u16*)(ws + WS_XB);
    u16*   H      = (u16*)(ws + WS_H);
    u16*   Wdt    = (u16*)(ws + WS_WDT);
    u16*   Wdst   = (u16*)(ws + WS_WDST);
    u16*   Wgut   = (u16*)(ws + WS_WGUT);
    u16*   Wgust  = (u16*)(ws + WS_WGUST);
    float* Y      = (float*)(ws + WS_Y);

    xrouter_kernel<<<256, 256, 0, stream>>>(X, Wr, bias, Xb, sel, wtsv);
    dispatch_kernel<<<1, 512, 0, stream>>>(sel, bucket, counts, offs, pos);
    transpose_cvt<<<dim3(16, 16, 27), 256, 0, stream>>>(
        Wg, Wu, Wd, Wgs, Wus, Wds, Wgut, Wdt, Wgust, Wdst);

    proj1<<<3584, 256, 0, stream>>>(Xb, Wgut, Wgust, H, bucket, counts, offs);
    proj2<<<2304, 256, 0, stream>>>(H, Wdt, Wdst, Y, counts, offs);
    combine_kernel<<<T_TOK, 256, 0, stream>>>(Y, pos, wtsv, out);
}